// Round 8
// baseline (269.100 us; speedup 1.0000x reference)
//
#include <hip/hip_runtime.h>
#include <cstdint>
#include <cstddef>

// ---------------------------------------------------------------------------
// GATExtractPart round 8:
//  - k_gh_ln: XA@W1 GEMM fused with bias+LN+ReLU+ss2/sd2 (hpre eliminated)
//  - k_scores_final: per-graph scores GEMM + tanh/va + softmax + pool + emb
//    (direct-global fragments, no LDS staging, 512 blocks x 8 waves)
// ---------------------------------------------------------------------------

#define LEAKY_SLOPE 0.2f

typedef __attribute__((ext_vector_type(8))) _Float16 half8;
typedef __attribute__((ext_vector_type(4))) float facc4;

__global__ void k_fold(const float* __restrict__ We1, const float* __restrict__ ae1,
                       const float* __restrict__ We2, const float* __restrict__ ae2,
                       const float* __restrict__ W1, const float* __restrict__ as1,
                       const float* __restrict__ ad1,
                       const float* __restrict__ W2, const float* __restrict__ as2,
                       const float* __restrict__ ad2, float* __restrict__ fold) {
    int t = blockIdx.x * blockDim.x + threadIdx.x;
    if (t < 24) {
        int k = t >> 2, h = t & 3;
        float s = 0.f;
        for (int c = 0; c < 256; ++c) s += We1[k * 1024 + h * 256 + c] * ae1[h * 256 + c];
        fold[t] = s;
    } else if (t >= 24 && t < 30) {
        int k = t - 24;
        float s = 0.f;
        for (int c = 0; c < 256; ++c) s += We2[k * 256 + c] * ae2[c];
        fold[32 + k] = s;
    } else if (t >= 64 && t < 284) {
        int i = t - 64, k = i >> 2, h = i & 3;
        float s = 0.f;
        for (int c = 0; c < 256; ++c) s += W1[k * 1024 + h * 256 + c] * as1[h * 256 + c];
        fold[64 + i] = s;
    } else if (t >= 320 && t < 540) {
        int i = t - 320, k = i >> 2, h = i & 3;
        float s = 0.f;
        for (int c = 0; c < 256; ++c) s += W1[k * 1024 + h * 256 + c] * ad1[h * 256 + c];
        fold[320 + i] = s;
    } else if (t >= 1024 && t < 2048) {
        int k = t - 1024;
        float s = 0.f;
        for (int c = 0; c < 256; ++c) s += W2[k * 256 + c] * as2[c];
        fold[1024 + k] = s;
    } else if (t >= 2048 && t < 3072) {
        int k = t - 2048;
        float s = 0.f;
        for (int c = 0; c < 256; ++c) s += W2[k * 256 + c] * ad2[c];
        fold[2048 + k] = s;
    }
}

__global__ void k_cast_w(const float* __restrict__ W1, const float* __restrict__ W2,
                         const float* __restrict__ Wa, _Float16* __restrict__ w1t,
                         _Float16* __restrict__ w2t, _Float16* __restrict__ wat) {
    int idx = blockIdx.x * blockDim.x + threadIdx.x;
    if (idx < 1024 * 64) {
        int c = idx >> 6, k = idx & 63;
        w1t[idx] = (k < 55) ? (_Float16)W1[(size_t)k * 1024 + c] : (_Float16)0.f;
    } else if (idx < 1024 * 64 + 256 * 1024) {
        int i = idx - 1024 * 64;
        int c = i >> 10, k = i & 1023;
        w2t[i] = (_Float16)W2[(size_t)k * 256 + c];
    } else if (idx < 1024 * 64 + 256 * 1024 + 256 * 256) {
        int i = idx - 1024 * 64 - 256 * 1024;
        int c = i >> 8, k = i & 255;
        wat[i] = (_Float16)Wa[(size_t)k * 256 + c];
    }
}

__global__ void k_cast_xt(const float* __restrict__ x, _Float16* __restrict__ xbT, int N) {
    int idx = blockIdx.x * blockDim.x + threadIdx.x;
    if (idx >= N * 64) return;
    int k = idx / N, n = idx - k * N;
    xbT[idx] = (k < 55) ? (_Float16)x[(size_t)n * 55 + k] : (_Float16)0.f;
}

__global__ void k_ssd1(const float* __restrict__ x, const float* __restrict__ wa1,
                       const float* __restrict__ wd1, float* __restrict__ ss1,
                       float* __restrict__ sd1, int N) {
    int n = blockIdx.x * blockDim.x + threadIdx.x;
    if (n >= N) return;
    float a0 = 0, a1 = 0, a2 = 0, a3 = 0, d0 = 0, d1 = 0, d2 = 0, d3 = 0;
    for (int k = 0; k < 55; ++k) {
        float xv = x[(size_t)n * 55 + k];
        float4 wa = *reinterpret_cast<const float4*>(&wa1[k * 4]);
        float4 wd = *reinterpret_cast<const float4*>(&wd1[k * 4]);
        a0 += xv * wa.x; a1 += xv * wa.y; a2 += xv * wa.z; a3 += xv * wa.w;
        d0 += xv * wd.x; d1 += xv * wd.y; d2 += xv * wd.z; d3 += xv * wd.w;
    }
    *reinterpret_cast<float4*>(&ss1[n * 4]) = make_float4(a0, a1, a2, a3);
    *reinterpret_cast<float4*>(&sd1[n * 4]) = make_float4(d0, d1, d2, d3);
}

__global__ void k_edge_accum(const int* __restrict__ ei, const float* __restrict__ ea,
                             int* __restrict__ deg, float* __restrict__ mea, int E) {
    int e = blockIdx.x * blockDim.x + threadIdx.x;
    if (e >= E) return;
    int d = ei[E + e];
    atomicAdd(&deg[d], 1);
#pragma unroll
    for (int k = 0; k < 6; ++k) atomicAdd(&mea[d * 6 + k], ea[e * 6 + k]);
}
__global__ void k_scan(const int* __restrict__ deg, int* __restrict__ off, int N) {
    __shared__ int part[1024];
    int t = threadIdx.x;
    int per = N / 1024;
    int base = t * per;
    int loc[32];
    int s = 0;
    for (int i = 0; i < per; ++i) { loc[i] = s; s += deg[base + i] + 1; }
    part[t] = s;
    __syncthreads();
    for (int o = 1; o < 1024; o <<= 1) {
        int v = (t >= o) ? part[t - o] : 0;
        __syncthreads();
        part[t] += v;
        __syncthreads();
    }
    int excl = (t == 0) ? 0 : part[t - 1];
    for (int i = 0; i < per; ++i) off[base + i] = excl + loc[i];
    if (t == 1023) off[N] = excl + s;
}
__global__ void k_fill(const int* __restrict__ ei, const int* __restrict__ coff,
                       int* __restrict__ fill, int* __restrict__ eid, int E, int Ef) {
    int e = blockIdx.x * blockDim.x + threadIdx.x;
    if (e >= Ef) return;
    int d = (e < E) ? ei[E + e] : (e - E);
    int pos = coff[d] + atomicAdd(&fill[d], 1);
    eid[pos] = e;
}
__global__ void k_eadot(const float* __restrict__ ea, const float* __restrict__ mea,
                        const int* __restrict__ deg,
                        const float* __restrict__ we1, const float* __restrict__ we2,
                        float* __restrict__ ead1, float* __restrict__ ead2, int E, int Ef) {
    int e = blockIdx.x * blockDim.x + threadIdx.x;
    if (e >= Ef) return;
    float buf[6];
    const float* eap;
    if (e < E) {
        eap = ea + (size_t)e * 6;
    } else {
        int n = e - E;
        float inv = 1.f / fmaxf((float)deg[n], 1.f);
#pragma unroll
        for (int k = 0; k < 6; ++k) buf[k] = mea[(size_t)n * 6 + k] * inv;
        eap = buf;
    }
    float v[4] = {};
    float v2 = 0.f;
#pragma unroll
    for (int k = 0; k < 6; ++k) {
        float a = eap[k];
#pragma unroll
        for (int h = 0; h < 4; ++h) v[h] += a * we1[k * 4 + h];
        v2 += a * we2[k];
    }
#pragma unroll
    for (int h = 0; h < 4; ++h) ead1[(size_t)e * 4 + h] = v[h];
    ead2[e] = v2;
}

__global__ __launch_bounds__(512) void k_pbuild1(
    const _Float16* __restrict__ xbT, int N,
    const int* __restrict__ coff, const int* __restrict__ eid, const int* __restrict__ ei,
    const float* __restrict__ ead1, const float* __restrict__ ss1,
    const float* __restrict__ sd1,
    _Float16* __restrict__ XA, int ldxa, int E, int g0) {
    __shared__ _Float16 Pm[4][64 * 64];
    __shared__ float llds[384][4];
    __shared__ int slds[384];
    int g = blockIdx.x;
    int ng = (g0 + g) * 64;
    int lr0 = g * 64;
    int tid = threadIdx.x;
    int lane = tid & 63, wid = tid >> 6;
    int l15 = lane & 15, l4 = lane >> 4;
    for (int i = tid; i < 4 * 64 * 64 / 8; i += 512)
        *reinterpret_cast<int4*>(&Pm[0][0] + i * 8) = int4{0, 0, 0, 0};
    int pbase = coff[ng];
    int pcnt = coff[ng + 64] - pbase;
    if (pcnt > 384) pcnt = 384;
    for (int p = tid; p < pcnt; p += 512) {
        int e = eid[pbase + p];
        int s, d;
        if (e < E) { s = ei[e]; d = ei[E + e]; } else { s = e - E; d = s; }
        slds[p] = s - ng;
        float4 sv = *reinterpret_cast<const float4*>(&ss1[s * 4]);
        float4 dv = *reinterpret_cast<const float4*>(&sd1[d * 4]);
        float4 ev = *reinterpret_cast<const float4*>(&ead1[(size_t)e * 4]);
        float v0 = sv.x + dv.x + ev.x, v1 = sv.y + dv.y + ev.y;
        float v2 = sv.z + dv.z + ev.z, v3 = sv.w + dv.w + ev.w;
        llds[p][0] = (v0 > 0.f) ? v0 : LEAKY_SLOPE * v0;
        llds[p][1] = (v1 > 0.f) ? v1 : LEAKY_SLOPE * v1;
        llds[p][2] = (v2 > 0.f) ? v2 : LEAKY_SLOPE * v2;
        llds[p][3] = (v3 > 0.f) ? v3 : LEAKY_SLOPE * v3;
    }
    __syncthreads();
    if (tid < 256) {
        int dst = tid >> 2, h = tid & 3;
        int p0 = coff[ng + dst] - pbase, p1 = coff[ng + dst + 1] - pbase;
        float m = -1e30f;
        for (int p = p0; p < p1; ++p) m = fmaxf(m, llds[p][h]);
        float sm = 0.f;
        for (int p = p0; p < p1; ++p) sm += expf(llds[p][h] - m);
        float iv = 1.f / (sm + 1e-16f);
        for (int p = p0; p < p1; ++p) {
            int src = slds[p];
            int pos = dst * 64 + (((src >> 3) ^ (dst & 7)) << 3) + (src & 7);
            Pm[h][pos] = (_Float16)((float)Pm[h][pos] + expf(llds[p][h] - m) * iv);
        }
    }
    __syncthreads();
    int head = wid >> 1, fjh = wid & 1;
    facc4 acc[4][2] = {};
#pragma unroll
    for (int kk = 0; kk < 2; ++kk) {
        half8 af[4], bf[2];
#pragma unroll
        for (int f = 0; f < 4; ++f) {
            int arow = f * 16 + l15;
            af[f] = *reinterpret_cast<const half8*>(
                &Pm[head][arow * 64 + (((kk * 4 + l4) ^ (arow & 7)) << 3)]);
        }
#pragma unroll
        for (int f = 0; f < 2; ++f) {
            int k2 = fjh * 32 + f * 16 + l15;
            bf[f] = *reinterpret_cast<const half8*>(
                xbT + (size_t)k2 * N + ng + kk * 32 + l4 * 8);
        }
#pragma unroll
        for (int fi = 0; fi < 4; ++fi)
#pragma unroll
            for (int fj = 0; fj < 2; ++fj)
                acc[fi][fj] = __builtin_amdgcn_mfma_f32_16x16x32_f16(
                    af[fi], bf[fj], acc[fi][fj], 0, 0, 0);
    }
#pragma unroll
    for (int fi = 0; fi < 4; ++fi)
#pragma unroll
        for (int fj = 0; fj < 2; ++fj)
#pragma unroll
            for (int i = 0; i < 4; ++i) {
                int r = fi * 16 + l4 * 4 + i;
                int k2 = fjh * 32 + fj * 16 + l15;
                XA[((size_t)head * ldxa + lr0 + r) * 64 + k2] = (_Float16)acc[fi][fj][i];
            }
}

// --- fused XA@W1 + bias + LN + ReLU + ss2/sd2 --------------------------------
// 512 threads = 8 waves; block covers 32 rows x 1024 cols.
// wave w: head = w>>1, col-half = w&1 -> cols [head*256 + (w&1)*128, +128)
__global__ __launch_bounds__(512) void k_gh_ln(
    const _Float16* __restrict__ XA, int ldxa, const _Float16* __restrict__ w1t,
    const float* __restrict__ b1, const float* __restrict__ g1,
    const float* __restrict__ be1,
    const float* __restrict__ w2a, const float* __restrict__ w2d,
    _Float16* __restrict__ hln, float* __restrict__ ss2, float* __restrict__ sd2,
    int n0) {
    __shared__ float rsum[32], rsq[32], r2a[32], r2d[32];
    int tid = threadIdx.x;
    int lane = tid & 63, wid = tid >> 6;
    int l15 = lane & 15, l4 = lane >> 4;
    int r0 = blockIdx.x * 32;
    int head = wid >> 1;
    int cbase = head * 256 + (wid & 1) * 128;
    if (tid < 32) { rsum[tid] = 0.f; rsq[tid] = 0.f; r2a[tid] = 0.f; r2d[tid] = 0.f; }
    __syncthreads();
    const _Float16* A = XA + (size_t)head * ldxa * 64;
    facc4 acc[2][8] = {};
#pragma unroll
    for (int kk = 0; kk < 2; ++kk) {
        half8 af[2], bf[8];
#pragma unroll
        for (int f = 0; f < 2; ++f)
            af[f] = *reinterpret_cast<const half8*>(
                A + (size_t)(r0 + f * 16 + l15) * 64 + kk * 32 + l4 * 8);
#pragma unroll
        for (int f = 0; f < 8; ++f)
            bf[f] = *reinterpret_cast<const half8*>(
                w1t + (size_t)(cbase + f * 16 + l15) * 64 + kk * 32 + l4 * 8);
#pragma unroll
        for (int fi = 0; fi < 2; ++fi)
#pragma unroll
            for (int fj = 0; fj < 8; ++fj)
                acc[fi][fj] = __builtin_amdgcn_mfma_f32_16x16x32_f16(
                    af[fi], bf[fj], acc[fi][fj], 0, 0, 0);
    }
    float bb[8];
#pragma unroll
    for (int fj = 0; fj < 8; ++fj) bb[fj] = b1[cbase + fj * 16 + l15];
#pragma unroll
    for (int fi = 0; fi < 2; ++fi)
#pragma unroll
        for (int i = 0; i < 4; ++i) {
            float s = 0.f, q = 0.f;
#pragma unroll
            for (int fj = 0; fj < 8; ++fj) {
                float v = acc[fi][fj][i] + bb[fj];
                acc[fi][fj][i] = v;
                s += v; q += v * v;
            }
            s += __shfl_xor(s, 1); q += __shfl_xor(q, 1);
            s += __shfl_xor(s, 2); q += __shfl_xor(q, 2);
            s += __shfl_xor(s, 4); q += __shfl_xor(q, 4);
            s += __shfl_xor(s, 8); q += __shfl_xor(q, 8);
            if (l15 == 0) {
                int r = fi * 16 + l4 * 4 + i;
                atomicAdd(&rsum[r], s);
                atomicAdd(&rsq[r], q);
            }
        }
    __syncthreads();
#pragma unroll
    for (int fi = 0; fi < 2; ++fi)
#pragma unroll
        for (int i = 0; i < 4; ++i) {
            int r = fi * 16 + l4 * 4 + i;
            float mu = rsum[r] * (1.f / 1024.f);
            float var = rsq[r] * (1.f / 1024.f) - mu * mu;
            float rstd = rsqrtf(var + 1e-5f);
            float s2 = 0.f, d2 = 0.f;
#pragma unroll
            for (int fj = 0; fj < 8; ++fj) {
                int c = cbase + fj * 16 + l15;
                float v = (acc[fi][fj][i] - mu) * rstd * g1[c] + be1[c];
                v = fmaxf(v, 0.f);
                hln[(size_t)(r0 + r) * 1024 + c] = (_Float16)v;
                s2 += v * w2a[c];
                d2 += v * w2d[c];
            }
            s2 += __shfl_xor(s2, 1); d2 += __shfl_xor(d2, 1);
            s2 += __shfl_xor(s2, 2); d2 += __shfl_xor(d2, 2);
            s2 += __shfl_xor(s2, 4); d2 += __shfl_xor(d2, 4);
            s2 += __shfl_xor(s2, 8); d2 += __shfl_xor(d2, 8);
            if (l15 == 0) { atomicAdd(&r2a[r], s2); atomicAdd(&r2d[r], d2); }
        }
    __syncthreads();
    if (tid < 32) { ss2[n0 + r0 + tid] = r2a[tid]; sd2[n0 + r0 + tid] = r2d[tid]; }
}

__global__ __launch_bounds__(256) void k_gemm2(
    const _Float16* __restrict__ A, const _Float16* __restrict__ BT,
    _Float16* __restrict__ C, int ldc) {
    __shared__ _Float16 As[128 * 64];
    __shared__ _Float16 Bs[128 * 64];
    int tid = threadIdx.x;
    int lane = tid & 63, wid = tid >> 6;
    int wr = wid >> 1, wc = wid & 1;
    int l15 = lane & 15, l4 = lane >> 4;
    int r0 = blockIdx.y * 128, c0 = blockIdx.x * 128;
    facc4 acc[4][4] = {};
    for (int kt = 0; kt < 1024; kt += 64) {
#pragma unroll
        for (int i = 0; i < 4; ++i) {
            int ch = tid + 256 * i;
            int row = ch >> 3, col16 = ch & 7;
            int sw = col16 ^ (row & 7);
            *reinterpret_cast<int4*>(&As[row * 64 + sw * 8]) =
                *reinterpret_cast<const int4*>(A + (size_t)(r0 + row) * 1024 + kt + col16 * 8);
            *reinterpret_cast<int4*>(&Bs[row * 64 + sw * 8]) =
                *reinterpret_cast<const int4*>(BT + (size_t)(c0 + row) * 1024 + kt + col16 * 8);
        }
        __syncthreads();
#pragma unroll
        for (int kk = 0; kk < 2; ++kk) {
            half8 af[4], bf[4];
#pragma unroll
            for (int f = 0; f < 4; ++f) {
                int arow = wr * 64 + f * 16 + l15;
                int ac = (kk * 4 + l4) ^ (arow & 7);
                af[f] = *reinterpret_cast<const half8*>(&As[arow * 64 + ac * 8]);
                int brow = wc * 64 + f * 16 + l15;
                int bc = (kk * 4 + l4) ^ (brow & 7);
                bf[f] = *reinterpret_cast<const half8*>(&Bs[brow * 64 + bc * 8]);
            }
#pragma unroll
            for (int fi = 0; fi < 4; ++fi)
#pragma unroll
                for (int fj = 0; fj < 4; ++fj)
                    acc[fi][fj] = __builtin_amdgcn_mfma_f32_16x16x32_f16(
                        af[fi], bf[fj], acc[fi][fj], 0, 0, 0);
        }
        __syncthreads();
    }
#pragma unroll
    for (int fi = 0; fi < 4; ++fi)
#pragma unroll
        for (int fj = 0; fj < 4; ++fj)
#pragma unroll
            for (int i = 0; i < 4; ++i) {
                int r = r0 + wr * 64 + fi * 16 + l4 * 4 + i;
                int cc = c0 + wc * 64 + fj * 16 + l15;
                C[(size_t)r * ldc + cc] = (_Float16)acc[fi][fj][i];
            }
}

__global__ __launch_bounds__(512) void k_graph2(
    const _Float16* __restrict__ h2t, int ldh,
    const int* __restrict__ coff, const int* __restrict__ eid, const int* __restrict__ ei,
    const float* __restrict__ ead2, const float* __restrict__ ss2,
    const float* __restrict__ sd2,
    const float* __restrict__ b2, const float* __restrict__ g2,
    const float* __restrict__ be2,
    float* __restrict__ hfc, _Float16* __restrict__ hfb, int E, int g0) {
    __shared__ _Float16 Pm[64 * 64];
    __shared__ float llds[384];
    __shared__ int slds[384];
    __shared__ float rsum[64], rsq[64];
    int g = blockIdx.x;
    int ng = (g0 + g) * 64;
    int lr0 = g * 64;
    int tid = threadIdx.x;
    int lane = tid & 63, wid = tid >> 6;
    int l15 = lane & 15, l4 = lane >> 4;
    if (tid < 64) { rsum[tid] = 0.f; rsq[tid] = 0.f; }
    for (int i = tid; i < 64 * 64 / 8; i += 512)
        *reinterpret_cast<int4*>(&Pm[0] + i * 8) = int4{0, 0, 0, 0};
    int pbase = coff[ng];
    int pcnt = coff[ng + 64] - pbase;
    if (pcnt > 384) pcnt = 384;
    for (int p = tid; p < pcnt; p += 512) {
        int e = eid[pbase + p];
        int s, d;
        if (e < E) { s = ei[e]; d = ei[E + e]; } else { s = e - E; d = s; }
        slds[p] = s - ng;
        float v = ss2[s] + sd2[d] + ead2[e];
        llds[p] = (v > 0.f) ? v : LEAKY_SLOPE * v;
    }
    __syncthreads();
    if (tid < 64) {
        int dst = tid;
        int p0 = coff[ng + dst] - pbase, p1 = coff[ng + dst + 1] - pbase;
        float m = -1e30f;
        for (int p = p0; p < p1; ++p) m = fmaxf(m, llds[p]);
        float sm = 0.f;
        for (int p = p0; p < p1; ++p) sm += expf(llds[p] - m);
        float iv = 1.f / (sm + 1e-16f);
        for (int p = p0; p < p1; ++p) {
            int src = slds[p];
            int pos = dst * 64 + (((src >> 3) ^ (dst & 7)) << 3) + (src & 7);
            Pm[pos] = (_Float16)((float)Pm[pos] + expf(llds[p] - m) * iv);
        }
    }
    __syncthreads();
    facc4 acc[4][2] = {};
    int cbase = wid * 32;
#pragma unroll
    for (int kk = 0; kk < 2; ++kk) {
        half8 af[4], bf[2];
#pragma unroll
        for (int f = 0; f < 4; ++f) {
            int arow = f * 16 + l15;
            af[f] = *reinterpret_cast<const half8*>(
                &Pm[arow * 64 + (((kk * 4 + l4) ^ (arow & 7)) << 3)]);
        }
#pragma unroll
        for (int f = 0; f < 2; ++f) {
            int c = cbase + f * 16 + l15;
            bf[f] = *reinterpret_cast<const half8*>(
                h2t + (size_t)c * ldh + lr0 + kk * 32 + l4 * 8);
        }
#pragma unroll
        for (int fi = 0; fi < 4; ++fi)
#pragma unroll
            for (int fj = 0; fj < 2; ++fj)
                acc[fi][fj] = __builtin_amdgcn_mfma_f32_16x16x32_f16(
                    af[fi], bf[fj], acc[fi][fj], 0, 0, 0);
    }
    float bb[2];
#pragma unroll
    for (int fj = 0; fj < 2; ++fj) bb[fj] = b2[cbase + fj * 16 + l15];
#pragma unroll
    for (int fi = 0; fi < 4; ++fi)
#pragma unroll
        for (int i = 0; i < 4; ++i) {
            float s = 0.f, q = 0.f;
#pragma unroll
            for (int fj = 0; fj < 2; ++fj) {
                float v = acc[fi][fj][i] + bb[fj];
                acc[fi][fj][i] = v;
                s += v; q += v * v;
            }
            s += __shfl_xor(s, 1); q += __shfl_xor(q, 1);
            s += __shfl_xor(s, 2); q += __shfl_xor(q, 2);
            s += __shfl_xor(s, 4); q += __shfl_xor(q, 4);
            s += __shfl_xor(s, 8); q += __shfl_xor(q, 8);
            if (l15 == 0) {
                int r = fi * 16 + l4 * 4 + i;
                atomicAdd(&rsum[r], s);
                atomicAdd(&rsq[r], q);
            }
        }
    __syncthreads();
#pragma unroll
    for (int fi = 0; fi < 4; ++fi)
#pragma unroll
        for (int i = 0; i < 4; ++i) {
            int r = fi * 16 + l4 * 4 + i;
            float mu = rsum[r] * (1.f / 256.f);
            float var = rsq[r] * (1.f / 256.f) - mu * mu;
            float rstd = rsqrtf(var + 1e-5f);
#pragma unroll
            for (int fj = 0; fj < 2; ++fj) {
                int c = cbase + fj * 16 + l15;
                float v = (acc[fi][fj][i] - mu) * rstd * g2[c] + be2[c];
                hfc[(size_t)(lr0 + r) * 256 + c] = v;
                hfb[(size_t)(lr0 + r) * 256 + c] = (_Float16)v;
            }
        }
}

// --- per-graph fused scores + softmax + pool + emb ---------------------------
// 512 threads = 8 waves; wave w owns 32 score-GEMM cols; rows = 64 (one graph).
// Direct-global MFMA fragments (hfb, wat both L2-resident).
__global__ __launch_bounds__(512) void k_scores_final(
    const _Float16* __restrict__ hfb, const _Float16* __restrict__ wat,
    const float* __restrict__ va, const float* __restrict__ hfc,
    const int* __restrict__ food, const float* __restrict__ emb,
    float* __restrict__ out, int B, int g0) {
    __shared__ float part[8][64];
    __shared__ float at[64];
    __shared__ float pmax[2][256];
    int g = blockIdx.x;
    int b = g0 + g;
    int r0 = g * 64;
    int tid = threadIdx.x;
    int lane = tid & 63, wid = tid >> 6;
    int l15 = lane & 15, l4 = lane >> 4;
    int cbase = wid * 32;
    facc4 acc[4][2] = {};
#pragma unroll
    for (int kk = 0; kk < 8; ++kk) {
        half8 af[4], bf[2];
#pragma unroll
        for (int f = 0; f < 4; ++f)
            af[f] = *reinterpret_cast<const half8*>(
                hfb + (size_t)(r0 + f * 16 + l15) * 256 + kk * 32 + l4 * 8);
#pragma unroll
        for (int f = 0; f < 2; ++f)
            bf[f] = *reinterpret_cast<const half8*>(
                wat + (size_t)(cbase + f * 16 + l15) * 256 + kk * 32 + l4 * 8);
#pragma unroll
        for (int fi = 0; fi < 4; ++fi)
#pragma unroll
            for (int fj = 0; fj < 2; ++fj)
                acc[fi][fj] = __builtin_amdgcn_mfma_f32_16x16x32_f16(
                    af[fi], bf[fj], acc[fi][fj], 0, 0, 0);
    }
    float vac[2];
#pragma unroll
    for (int fj = 0; fj < 2; ++fj) vac[fj] = va[cbase + fj * 16 + l15];
#pragma unroll
    for (int fi = 0; fi < 4; ++fi)
#pragma unroll
        for (int i = 0; i < 4; ++i) {
            float v = tanhf(acc[fi][0][i]) * vac[0] + tanhf(acc[fi][1][i]) * vac[1];
            v += __shfl_xor(v, 1); v += __shfl_xor(v, 2);
            v += __shfl_xor(v, 4); v += __shfl_xor(v, 8);
            if (l15 == 0) part[wid][fi * 16 + l4 * 4 + i] = v;
        }
    __syncthreads();
    if (tid < 64) {
        float sc = part[0][tid] + part[1][tid] + part[2][tid] + part[3][tid] +
                   part[4][tid] + part[5][tid] + part[6][tid] + part[7][tid];
        float m = sc;
        for (int o = 32; o; o >>= 1) m = fmaxf(m, __shfl_xor(m, o));
        float ex = expf(sc - m);
        float s = ex;
        for (int o = 32; o; o >>= 1) s += __shfl_xor(s, o);
        float a = ex / (s + 1e-16f);
        at[tid] = a;
        out[(size_t)B * 512 + (size_t)b * 64 + tid] = a;      // attn
    }
    __syncthreads();
    {
        int c = tid & 255, half = tid >> 8;
        float m = -1e30f;
        for (int l = half * 32; l < half * 32 + 32; ++l)
            m = fmaxf(m, hfc[(size_t)(r0 + l) * 256 + c] * at[l]);
        pmax[half][c] = m;
    }
    __syncthreads();
    if (tid < 256) {
        out[(size_t)b * 256 + tid] = fmaxf(pmax[0][tid], pmax[1][tid]);   // drug_fea
        out[(size_t)B * 256 + (size_t)b * 256 + tid] =
            emb[(size_t)food[b] * 256 + tid];                              // food_fea
    }
}

// ---------------------------------------------------------------------------
extern "C" void kernel_launch(void* const* d_in, const int* in_sizes, int n_in,
                              void* d_out, int out_size, void* d_ws, size_t ws_size,
                              hipStream_t stream) {
    const float* x   = (const float*)d_in[0];
    const float* ea  = (const float*)d_in[1];
    const int*   ei  = (const int*)d_in[2];
    const int*   food= (const int*)d_in[4];
    const float* W1  = (const float*)d_in[5];
    const float* as1 = (const float*)d_in[6];
    const float* ad1 = (const float*)d_in[7];
    const float* We1 = (const float*)d_in[8];
    const float* ae1 = (const float*)d_in[9];
    const float* b1  = (const float*)d_in[10];
    const float* g1  = (const float*)d_in[11];
    const float* be1 = (const float*)d_in[12];
    const float* W2  = (const float*)d_in[13];
    const float* as2 = (const float*)d_in[14];
    const float* ad2 = (const float*)d_in[15];
    const float* We2 = (const float*)d_in[16];
    const float* ae2 = (const float*)d_in[17];
    const float* b2  = (const float*)d_in[18];
    const float* g2  = (const float*)d_in[19];
    const float* be2 = (const float*)d_in[20];
    const float* Wa  = (const float*)d_in[21];
    const float* va  = (const float*)d_in[22];
    const float* emb = (const float*)d_in[23];
    float* out = (float*)d_out;

    const int N  = in_sizes[0] / 55;
    const int E  = in_sizes[2] / 2;
    const int B  = in_sizes[4];
    const int Ef = E + N;
    const int LPG = N / B;

    char* w = (char*)d_ws;
    size_t off = 0;
    auto take = [&](size_t bytes) -> char* {
        char* p = w + off;
        off = (off + bytes + 255) & ~(size_t)255;
        return p;
    };
    int*      deg  = (int*)take((size_t)N * 4);
    float*    mea  = (float*)take((size_t)N * 6 * 4);
    int*      coff = (int*)take((size_t)(N + 1) * 4);
    int*      fill = (int*)take((size_t)N * 4);
    int*      eid  = (int*)take((size_t)Ef * 4);
    float*    ead1 = (float*)take((size_t)Ef * 4 * 4);
    float*    ead2 = (float*)take((size_t)Ef * 4);
    float*    fold = (float*)take(4096 * 4);
    float*    ss1  = (float*)take((size_t)N * 4 * 4);
    float*    sd1  = (float*)take((size_t)N * 4 * 4);
    float*    ss2  = (float*)take((size_t)N * 4);
    float*    sd2  = (float*)take((size_t)N * 4);
    _Float16* xbT  = (_Float16*)take((size_t)N * 64 * 2);
    _Float16* w1t  = (_Float16*)take((size_t)1024 * 64 * 2);
    _Float16* w2t  = (_Float16*)take((size_t)256 * 1024 * 2);
    _Float16* wat  = (_Float16*)take((size_t)256 * 256 * 2);
    size_t smallEnd = off;

    int G = B;
    while (G > 2 && smallEnd + (size_t)G * 32768 + 2ull * G * 131072 + 768 > ws_size) G >>= 1;
    _Float16* XA   = (_Float16*)take((size_t)G * 32768);
    _Float16* hpre = (_Float16*)take((size_t)G * 131072);   // overlay region
    _Float16* hln  = (_Float16*)take((size_t)G * 131072);
    _Float16* h2t = hpre;
    float*    hfc = (float*)((char*)hpre + (size_t)G * 32768);
    _Float16* hfb = (_Float16*)((char*)hpre + (size_t)G * 98304);

    hipMemsetAsync(deg, 0, (size_t)N * 4, stream);
    hipMemsetAsync(mea, 0, (size_t)N * 6 * 4, stream);
    hipMemsetAsync(fill, 0, (size_t)N * 4, stream);

    k_fold<<<12, 256, 0, stream>>>(We1, ae1, We2, ae2, W1, as1, ad1, W2, as2, ad2, fold);
    k_cast_w<<<(1024 * 64 + 256 * 1024 + 256 * 256 + 255) / 256, 256, 0, stream>>>(
        W1, W2, Wa, w1t, w2t, wat);
    k_cast_xt<<<(N * 64 + 255) / 256, 256, 0, stream>>>(x, xbT, N);
    k_ssd1<<<(N + 255) / 256, 256, 0, stream>>>(x, fold + 64, fold + 320, ss1, sd1, N);
    k_edge_accum<<<(E + 255) / 256, 256, 0, stream>>>(ei, ea, deg, mea, E);
    k_scan<<<1, 1024, 0, stream>>>(deg, coff, N);
    k_fill<<<(Ef + 255) / 256, 256, 0, stream>>>(ei, coff, fill, eid, E, Ef);
    k_eadot<<<(Ef + 255) / 256, 256, 0, stream>>>(ea, mea, deg, fold, fold + 32,
                                                  ead1, ead2, E, Ef);

    for (int g0 = 0; g0 < B; g0 += G) {
        int Gc = (g0 + G <= B) ? G : (B - g0);
        int n0 = g0 * LPG;
        int NC = Gc * LPG;
        k_pbuild1<<<Gc, 512, 0, stream>>>(xbT, N, coff, eid, ei, ead1, ss1, sd1,
                                          XA, NC, E, g0);
        k_gh_ln<<<NC / 32, 512, 0, stream>>>(XA, NC, w1t, b1, g1, be1,
                                             fold + 1024, fold + 2048,
                                             hln, ss2, sd2, n0);
        k_gemm2<<<dim3(NC / 128, 2), 256, 0, stream>>>(w2t, hln, h2t, NC);
        k_graph2<<<Gc, 512, 0, stream>>>(h2t, NC, coff, eid, ei, ead2, ss2, sd2,
                                         b2, g2, be2, hfc, hfb, E, g0);
        k_scores_final<<<Gc, 512, 0, stream>>>(hfb, wat, va, hfc, food, emb,
                                               out, B, g0);
    }
}

// Round 9
// 259.829 us; speedup vs baseline: 1.0357x; 1.0357x over previous
//
#include <hip/hip_runtime.h>
#include <cstdint>
#include <cstddef>

// ---------------------------------------------------------------------------
// GATExtractPart round 9: round-7 split gemm_heads+ln1 (proven fast) +
// round-8 fused k_scores_final (proven fast). One variable per experiment.
// ---------------------------------------------------------------------------

#define LEAKY_SLOPE 0.2f

typedef __attribute__((ext_vector_type(8))) _Float16 half8;
typedef __attribute__((ext_vector_type(4))) float facc4;

__global__ void k_fold(const float* __restrict__ We1, const float* __restrict__ ae1,
                       const float* __restrict__ We2, const float* __restrict__ ae2,
                       const float* __restrict__ W1, const float* __restrict__ as1,
                       const float* __restrict__ ad1,
                       const float* __restrict__ W2, const float* __restrict__ as2,
                       const float* __restrict__ ad2, float* __restrict__ fold) {
    int t = blockIdx.x * blockDim.x + threadIdx.x;
    if (t < 24) {
        int k = t >> 2, h = t & 3;
        float s = 0.f;
        for (int c = 0; c < 256; ++c) s += We1[k * 1024 + h * 256 + c] * ae1[h * 256 + c];
        fold[t] = s;
    } else if (t >= 24 && t < 30) {
        int k = t - 24;
        float s = 0.f;
        for (int c = 0; c < 256; ++c) s += We2[k * 256 + c] * ae2[c];
        fold[32 + k] = s;
    } else if (t >= 64 && t < 284) {
        int i = t - 64, k = i >> 2, h = i & 3;
        float s = 0.f;
        for (int c = 0; c < 256; ++c) s += W1[k * 1024 + h * 256 + c] * as1[h * 256 + c];
        fold[64 + i] = s;
    } else if (t >= 320 && t < 540) {
        int i = t - 320, k = i >> 2, h = i & 3;
        float s = 0.f;
        for (int c = 0; c < 256; ++c) s += W1[k * 1024 + h * 256 + c] * ad1[h * 256 + c];
        fold[320 + i] = s;
    } else if (t >= 1024 && t < 2048) {
        int k = t - 1024;
        float s = 0.f;
        for (int c = 0; c < 256; ++c) s += W2[k * 256 + c] * as2[c];
        fold[1024 + k] = s;
    } else if (t >= 2048 && t < 3072) {
        int k = t - 2048;
        float s = 0.f;
        for (int c = 0; c < 256; ++c) s += W2[k * 256 + c] * ad2[c];
        fold[2048 + k] = s;
    }
}

__global__ void k_cast_w(const float* __restrict__ W1, const float* __restrict__ W2,
                         const float* __restrict__ Wa, _Float16* __restrict__ w1t,
                         _Float16* __restrict__ w2t, _Float16* __restrict__ wat) {
    int idx = blockIdx.x * blockDim.x + threadIdx.x;
    if (idx < 1024 * 64) {
        int c = idx >> 6, k = idx & 63;
        w1t[idx] = (k < 55) ? (_Float16)W1[(size_t)k * 1024 + c] : (_Float16)0.f;
    } else if (idx < 1024 * 64 + 256 * 1024) {
        int i = idx - 1024 * 64;
        int c = i >> 10, k = i & 1023;
        w2t[i] = (_Float16)W2[(size_t)k * 256 + c];
    } else if (idx < 1024 * 64 + 256 * 1024 + 256 * 256) {
        int i = idx - 1024 * 64 - 256 * 1024;
        int c = i >> 8, k = i & 255;
        wat[i] = (_Float16)Wa[(size_t)k * 256 + c];
    }
}

__global__ void k_cast_xt(const float* __restrict__ x, _Float16* __restrict__ xbT, int N) {
    int idx = blockIdx.x * blockDim.x + threadIdx.x;
    if (idx >= N * 64) return;
    int k = idx / N, n = idx - k * N;
    xbT[idx] = (k < 55) ? (_Float16)x[(size_t)n * 55 + k] : (_Float16)0.f;
}

__global__ void k_ssd1(const float* __restrict__ x, const float* __restrict__ wa1,
                       const float* __restrict__ wd1, float* __restrict__ ss1,
                       float* __restrict__ sd1, int N) {
    int n = blockIdx.x * blockDim.x + threadIdx.x;
    if (n >= N) return;
    float a0 = 0, a1 = 0, a2 = 0, a3 = 0, d0 = 0, d1 = 0, d2 = 0, d3 = 0;
    for (int k = 0; k < 55; ++k) {
        float xv = x[(size_t)n * 55 + k];
        float4 wa = *reinterpret_cast<const float4*>(&wa1[k * 4]);
        float4 wd = *reinterpret_cast<const float4*>(&wd1[k * 4]);
        a0 += xv * wa.x; a1 += xv * wa.y; a2 += xv * wa.z; a3 += xv * wa.w;
        d0 += xv * wd.x; d1 += xv * wd.y; d2 += xv * wd.z; d3 += xv * wd.w;
    }
    *reinterpret_cast<float4*>(&ss1[n * 4]) = make_float4(a0, a1, a2, a3);
    *reinterpret_cast<float4*>(&sd1[n * 4]) = make_float4(d0, d1, d2, d3);
}

__global__ void k_edge_accum(const int* __restrict__ ei, const float* __restrict__ ea,
                             int* __restrict__ deg, float* __restrict__ mea, int E) {
    int e = blockIdx.x * blockDim.x + threadIdx.x;
    if (e >= E) return;
    int d = ei[E + e];
    atomicAdd(&deg[d], 1);
#pragma unroll
    for (int k = 0; k < 6; ++k) atomicAdd(&mea[d * 6 + k], ea[e * 6 + k]);
}
__global__ void k_scan(const int* __restrict__ deg, int* __restrict__ off, int N) {
    __shared__ int part[1024];
    int t = threadIdx.x;
    int per = N / 1024;
    int base = t * per;
    int loc[32];
    int s = 0;
    for (int i = 0; i < per; ++i) { loc[i] = s; s += deg[base + i] + 1; }
    part[t] = s;
    __syncthreads();
    for (int o = 1; o < 1024; o <<= 1) {
        int v = (t >= o) ? part[t - o] : 0;
        __syncthreads();
        part[t] += v;
        __syncthreads();
    }
    int excl = (t == 0) ? 0 : part[t - 1];
    for (int i = 0; i < per; ++i) off[base + i] = excl + loc[i];
    if (t == 1023) off[N] = excl + s;
}
__global__ void k_fill(const int* __restrict__ ei, const int* __restrict__ coff,
                       int* __restrict__ fill, int* __restrict__ eid, int E, int Ef) {
    int e = blockIdx.x * blockDim.x + threadIdx.x;
    if (e >= Ef) return;
    int d = (e < E) ? ei[E + e] : (e - E);
    int pos = coff[d] + atomicAdd(&fill[d], 1);
    eid[pos] = e;
}
__global__ void k_eadot(const float* __restrict__ ea, const float* __restrict__ mea,
                        const int* __restrict__ deg,
                        const float* __restrict__ we1, const float* __restrict__ we2,
                        float* __restrict__ ead1, float* __restrict__ ead2, int E, int Ef) {
    int e = blockIdx.x * blockDim.x + threadIdx.x;
    if (e >= Ef) return;
    float buf[6];
    const float* eap;
    if (e < E) {
        eap = ea + (size_t)e * 6;
    } else {
        int n = e - E;
        float inv = 1.f / fmaxf((float)deg[n], 1.f);
#pragma unroll
        for (int k = 0; k < 6; ++k) buf[k] = mea[(size_t)n * 6 + k] * inv;
        eap = buf;
    }
    float v[4] = {};
    float v2 = 0.f;
#pragma unroll
    for (int k = 0; k < 6; ++k) {
        float a = eap[k];
#pragma unroll
        for (int h = 0; h < 4; ++h) v[h] += a * we1[k * 4 + h];
        v2 += a * we2[k];
    }
#pragma unroll
    for (int h = 0; h < 4; ++h) ead1[(size_t)e * 4 + h] = v[h];
    ead2[e] = v2;
}

__global__ __launch_bounds__(512) void k_pbuild1(
    const _Float16* __restrict__ xbT, int N,
    const int* __restrict__ coff, const int* __restrict__ eid, const int* __restrict__ ei,
    const float* __restrict__ ead1, const float* __restrict__ ss1,
    const float* __restrict__ sd1,
    _Float16* __restrict__ XA, int ldxa, int E, int g0) {
    __shared__ _Float16 Pm[4][64 * 64];
    __shared__ float llds[384][4];
    __shared__ int slds[384];
    int g = blockIdx.x;
    int ng = (g0 + g) * 64;
    int lr0 = g * 64;
    int tid = threadIdx.x;
    int lane = tid & 63, wid = tid >> 6;
    int l15 = lane & 15, l4 = lane >> 4;
    for (int i = tid; i < 4 * 64 * 64 / 8; i += 512)
        *reinterpret_cast<int4*>(&Pm[0][0] + i * 8) = int4{0, 0, 0, 0};
    int pbase = coff[ng];
    int pcnt = coff[ng + 64] - pbase;
    if (pcnt > 384) pcnt = 384;
    for (int p = tid; p < pcnt; p += 512) {
        int e = eid[pbase + p];
        int s, d;
        if (e < E) { s = ei[e]; d = ei[E + e]; } else { s = e - E; d = s; }
        slds[p] = s - ng;
        float4 sv = *reinterpret_cast<const float4*>(&ss1[s * 4]);
        float4 dv = *reinterpret_cast<const float4*>(&sd1[d * 4]);
        float4 ev = *reinterpret_cast<const float4*>(&ead1[(size_t)e * 4]);
        float v0 = sv.x + dv.x + ev.x, v1 = sv.y + dv.y + ev.y;
        float v2 = sv.z + dv.z + ev.z, v3 = sv.w + dv.w + ev.w;
        llds[p][0] = (v0 > 0.f) ? v0 : LEAKY_SLOPE * v0;
        llds[p][1] = (v1 > 0.f) ? v1 : LEAKY_SLOPE * v1;
        llds[p][2] = (v2 > 0.f) ? v2 : LEAKY_SLOPE * v2;
        llds[p][3] = (v3 > 0.f) ? v3 : LEAKY_SLOPE * v3;
    }
    __syncthreads();
    if (tid < 256) {
        int dst = tid >> 2, h = tid & 3;
        int p0 = coff[ng + dst] - pbase, p1 = coff[ng + dst + 1] - pbase;
        float m = -1e30f;
        for (int p = p0; p < p1; ++p) m = fmaxf(m, llds[p][h]);
        float sm = 0.f;
        for (int p = p0; p < p1; ++p) sm += expf(llds[p][h] - m);
        float iv = 1.f / (sm + 1e-16f);
        for (int p = p0; p < p1; ++p) {
            int src = slds[p];
            int pos = dst * 64 + (((src >> 3) ^ (dst & 7)) << 3) + (src & 7);
            Pm[h][pos] = (_Float16)((float)Pm[h][pos] + expf(llds[p][h] - m) * iv);
        }
    }
    __syncthreads();
    int head = wid >> 1, fjh = wid & 1;
    facc4 acc[4][2] = {};
#pragma unroll
    for (int kk = 0; kk < 2; ++kk) {
        half8 af[4], bf[2];
#pragma unroll
        for (int f = 0; f < 4; ++f) {
            int arow = f * 16 + l15;
            af[f] = *reinterpret_cast<const half8*>(
                &Pm[head][arow * 64 + (((kk * 4 + l4) ^ (arow & 7)) << 3)]);
        }
#pragma unroll
        for (int f = 0; f < 2; ++f) {
            int k2 = fjh * 32 + f * 16 + l15;
            bf[f] = *reinterpret_cast<const half8*>(
                xbT + (size_t)k2 * N + ng + kk * 32 + l4 * 8);
        }
#pragma unroll
        for (int fi = 0; fi < 4; ++fi)
#pragma unroll
            for (int fj = 0; fj < 2; ++fj)
                acc[fi][fj] = __builtin_amdgcn_mfma_f32_16x16x32_f16(
                    af[fi], bf[fj], acc[fi][fj], 0, 0, 0);
    }
#pragma unroll
    for (int fi = 0; fi < 4; ++fi)
#pragma unroll
        for (int fj = 0; fj < 2; ++fj)
#pragma unroll
            for (int i = 0; i < 4; ++i) {
                int r = fi * 16 + l4 * 4 + i;
                int k2 = fjh * 32 + fj * 16 + l15;
                XA[((size_t)head * ldxa + lr0 + r) * 64 + k2] = (_Float16)acc[fi][fj][i];
            }
}

__global__ __launch_bounds__(256) void k_gemm_heads(
    const _Float16* __restrict__ XA, int ldxa, const _Float16* __restrict__ w1t,
    _Float16* __restrict__ hpre) {
    int h = blockIdx.z;
    const _Float16* A = XA + (size_t)h * ldxa * 64;
    const _Float16* BT = w1t + (size_t)h * 256 * 64;
    __shared__ _Float16 As[128 * 64];
    __shared__ _Float16 Bs[128 * 64];
    int tid = threadIdx.x;
    int lane = tid & 63, wid = tid >> 6;
    int wr = wid >> 1, wc = wid & 1;
    int l15 = lane & 15, l4 = lane >> 4;
    int r0 = blockIdx.y * 128, c0 = blockIdx.x * 128;
    facc4 acc[4][4] = {};
#pragma unroll
    for (int i = 0; i < 4; ++i) {
        int ch = tid + 256 * i;
        int row = ch >> 3, col16 = ch & 7;
        int sw = col16 ^ (row & 7);
        *reinterpret_cast<int4*>(&As[row * 64 + sw * 8]) =
            *reinterpret_cast<const int4*>(A + (size_t)(r0 + row) * 64 + col16 * 8);
        *reinterpret_cast<int4*>(&Bs[row * 64 + sw * 8]) =
            *reinterpret_cast<const int4*>(BT + (size_t)(c0 + row) * 64 + col16 * 8);
    }
    __syncthreads();
#pragma unroll
    for (int kk = 0; kk < 2; ++kk) {
        half8 af[4], bf[4];
#pragma unroll
        for (int f = 0; f < 4; ++f) {
            int arow = wr * 64 + f * 16 + l15;
            int ac = (kk * 4 + l4) ^ (arow & 7);
            af[f] = *reinterpret_cast<const half8*>(&As[arow * 64 + ac * 8]);
            int brow = wc * 64 + f * 16 + l15;
            int bc = (kk * 4 + l4) ^ (brow & 7);
            bf[f] = *reinterpret_cast<const half8*>(&Bs[brow * 64 + bc * 8]);
        }
#pragma unroll
        for (int fi = 0; fi < 4; ++fi)
#pragma unroll
            for (int fj = 0; fj < 4; ++fj)
                acc[fi][fj] = __builtin_amdgcn_mfma_f32_16x16x32_f16(
                    af[fi], bf[fj], acc[fi][fj], 0, 0, 0);
    }
#pragma unroll
    for (int fi = 0; fi < 4; ++fi)
#pragma unroll
        for (int fj = 0; fj < 4; ++fj)
#pragma unroll
            for (int i = 0; i < 4; ++i) {
                int r = r0 + wr * 64 + fi * 16 + l4 * 4 + i;
                int cc = h * 256 + c0 + wc * 64 + fj * 16 + l15;
                hpre[(size_t)r * 1024 + cc] = (_Float16)acc[fi][fj][i];
            }
}

__global__ __launch_bounds__(256) void k_ln1(
    const _Float16* __restrict__ hpre, const float* __restrict__ b1,
    const float* __restrict__ g1, const float* __restrict__ be1,
    const float* __restrict__ w2a, const float* __restrict__ w2d,
    _Float16* __restrict__ hln, float* __restrict__ ss2, float* __restrict__ sd2,
    int n0) {
    int row = blockIdx.x * 4 + (threadIdx.x >> 6);
    int lane = threadIdx.x & 63;
    const _Float16* src = hpre + (size_t)row * 1024;
    float v[16];
    half8 h0 = *reinterpret_cast<const half8*>(src + lane * 8);
    half8 h1 = *reinterpret_cast<const half8*>(src + 512 + lane * 8);
    float lsum = 0.f, lsq = 0.f;
#pragma unroll
    for (int j = 0; j < 8; ++j) {
        v[j] = (float)h0[j] + b1[lane * 8 + j];
        v[8 + j] = (float)h1[j] + b1[512 + lane * 8 + j];
    }
#pragma unroll
    for (int j = 0; j < 16; ++j) { lsum += v[j]; lsq += v[j] * v[j]; }
    for (int o = 32; o; o >>= 1) { lsum += __shfl_xor(lsum, o); lsq += __shfl_xor(lsq, o); }
    float mu = lsum * (1.f / 1024.f);
    float var = lsq * (1.f / 1024.f) - mu * mu;
    float rstd = rsqrtf(var + 1e-5f);
    float s2 = 0.f, d2 = 0.f;
    half8 o0, o1;
#pragma unroll
    for (int j = 0; j < 8; ++j) {
        int c = lane * 8 + j;
        float t = fmaxf((v[j] - mu) * rstd * g1[c] + be1[c], 0.f);
        o0[j] = (_Float16)t;
        s2 += t * w2a[c]; d2 += t * w2d[c];
    }
#pragma unroll
    for (int j = 0; j < 8; ++j) {
        int c = 512 + lane * 8 + j;
        float t = fmaxf((v[8 + j] - mu) * rstd * g1[c] + be1[c], 0.f);
        o1[j] = (_Float16)t;
        s2 += t * w2a[c]; d2 += t * w2d[c];
    }
    *reinterpret_cast<half8*>(hln + (size_t)row * 1024 + lane * 8) = o0;
    *reinterpret_cast<half8*>(hln + (size_t)row * 1024 + 512 + lane * 8) = o1;
    for (int o = 32; o; o >>= 1) { s2 += __shfl_xor(s2, o); d2 += __shfl_xor(d2, o); }
    if (lane == 0) { ss2[n0 + row] = s2; sd2[n0 + row] = d2; }
}

__global__ __launch_bounds__(256) void k_gemm2(
    const _Float16* __restrict__ A, const _Float16* __restrict__ BT,
    _Float16* __restrict__ C, int ldc) {
    __shared__ _Float16 As[128 * 64];
    __shared__ _Float16 Bs[128 * 64];
    int tid = threadIdx.x;
    int lane = tid & 63, wid = tid >> 6;
    int wr = wid >> 1, wc = wid & 1;
    int l15 = lane & 15, l4 = lane >> 4;
    int r0 = blockIdx.y * 128, c0 = blockIdx.x * 128;
    facc4 acc[4][4] = {};
    for (int kt = 0; kt < 1024; kt += 64) {
#pragma unroll
        for (int i = 0; i < 4; ++i) {
            int ch = tid + 256 * i;
            int row = ch >> 3, col16 = ch & 7;
            int sw = col16 ^ (row & 7);
            *reinterpret_cast<int4*>(&As[row * 64 + sw * 8]) =
                *reinterpret_cast<const int4*>(A + (size_t)(r0 + row) * 1024 + kt + col16 * 8);
            *reinterpret_cast<int4*>(&Bs[row * 64 + sw * 8]) =
                *reinterpret_cast<const int4*>(BT + (size_t)(c0 + row) * 1024 + kt + col16 * 8);
        }
        __syncthreads();
#pragma unroll
        for (int kk = 0; kk < 2; ++kk) {
            half8 af[4], bf[4];
#pragma unroll
            for (int f = 0; f < 4; ++f) {
                int arow = wr * 64 + f * 16 + l15;
                int ac = (kk * 4 + l4) ^ (arow & 7);
                af[f] = *reinterpret_cast<const half8*>(&As[arow * 64 + ac * 8]);
                int brow = wc * 64 + f * 16 + l15;
                int bc = (kk * 4 + l4) ^ (brow & 7);
                bf[f] = *reinterpret_cast<const half8*>(&Bs[brow * 64 + bc * 8]);
            }
#pragma unroll
            for (int fi = 0; fi < 4; ++fi)
#pragma unroll
                for (int fj = 0; fj < 4; ++fj)
                    acc[fi][fj] = __builtin_amdgcn_mfma_f32_16x16x32_f16(
                        af[fi], bf[fj], acc[fi][fj], 0, 0, 0);
        }
        __syncthreads();
    }
#pragma unroll
    for (int fi = 0; fi < 4; ++fi)
#pragma unroll
        for (int fj = 0; fj < 4; ++fj)
#pragma unroll
            for (int i = 0; i < 4; ++i) {
                int r = r0 + wr * 64 + fi * 16 + l4 * 4 + i;
                int cc = c0 + wc * 64 + fj * 16 + l15;
                C[(size_t)r * ldc + cc] = (_Float16)acc[fi][fj][i];
            }
}

__global__ __launch_bounds__(512) void k_graph2(
    const _Float16* __restrict__ h2t, int ldh,
    const int* __restrict__ coff, const int* __restrict__ eid, const int* __restrict__ ei,
    const float* __restrict__ ead2, const float* __restrict__ ss2,
    const float* __restrict__ sd2,
    const float* __restrict__ b2, const float* __restrict__ g2,
    const float* __restrict__ be2,
    float* __restrict__ hfc, _Float16* __restrict__ hfb, int E, int g0) {
    __shared__ _Float16 Pm[64 * 64];
    __shared__ float llds[384];
    __shared__ int slds[384];
    __shared__ float rsum[64], rsq[64];
    int g = blockIdx.x;
    int ng = (g0 + g) * 64;
    int lr0 = g * 64;
    int tid = threadIdx.x;
    int lane = tid & 63, wid = tid >> 6;
    int l15 = lane & 15, l4 = lane >> 4;
    if (tid < 64) { rsum[tid] = 0.f; rsq[tid] = 0.f; }
    for (int i = tid; i < 64 * 64 / 8; i += 512)
        *reinterpret_cast<int4*>(&Pm[0] + i * 8) = int4{0, 0, 0, 0};
    int pbase = coff[ng];
    int pcnt = coff[ng + 64] - pbase;
    if (pcnt > 384) pcnt = 384;
    for (int p = tid; p < pcnt; p += 512) {
        int e = eid[pbase + p];
        int s, d;
        if (e < E) { s = ei[e]; d = ei[E + e]; } else { s = e - E; d = s; }
        slds[p] = s - ng;
        float v = ss2[s] + sd2[d] + ead2[e];
        llds[p] = (v > 0.f) ? v : LEAKY_SLOPE * v;
    }
    __syncthreads();
    if (tid < 64) {
        int dst = tid;
        int p0 = coff[ng + dst] - pbase, p1 = coff[ng + dst + 1] - pbase;
        float m = -1e30f;
        for (int p = p0; p < p1; ++p) m = fmaxf(m, llds[p]);
        float sm = 0.f;
        for (int p = p0; p < p1; ++p) sm += expf(llds[p] - m);
        float iv = 1.f / (sm + 1e-16f);
        for (int p = p0; p < p1; ++p) {
            int src = slds[p];
            int pos = dst * 64 + (((src >> 3) ^ (dst & 7)) << 3) + (src & 7);
            Pm[pos] = (_Float16)((float)Pm[pos] + expf(llds[p] - m) * iv);
        }
    }
    __syncthreads();
    facc4 acc[4][2] = {};
    int cbase = wid * 32;
#pragma unroll
    for (int kk = 0; kk < 2; ++kk) {
        half8 af[4], bf[2];
#pragma unroll
        for (int f = 0; f < 4; ++f) {
            int arow = f * 16 + l15;
            af[f] = *reinterpret_cast<const half8*>(
                &Pm[arow * 64 + (((kk * 4 + l4) ^ (arow & 7)) << 3)]);
        }
#pragma unroll
        for (int f = 0; f < 2; ++f) {
            int c = cbase + f * 16 + l15;
            bf[f] = *reinterpret_cast<const half8*>(
                h2t + (size_t)c * ldh + lr0 + kk * 32 + l4 * 8);
        }
#pragma unroll
        for (int fi = 0; fi < 4; ++fi)
#pragma unroll
            for (int fj = 0; fj < 2; ++fj)
                acc[fi][fj] = __builtin_amdgcn_mfma_f32_16x16x32_f16(
                    af[fi], bf[fj], acc[fi][fj], 0, 0, 0);
    }
    float bb[2];
#pragma unroll
    for (int fj = 0; fj < 2; ++fj) bb[fj] = b2[cbase + fj * 16 + l15];
#pragma unroll
    for (int fi = 0; fi < 4; ++fi)
#pragma unroll
        for (int i = 0; i < 4; ++i) {
            float s = 0.f, q = 0.f;
#pragma unroll
            for (int fj = 0; fj < 2; ++fj) {
                float v = acc[fi][fj][i] + bb[fj];
                acc[fi][fj][i] = v;
                s += v; q += v * v;
            }
            s += __shfl_xor(s, 1); q += __shfl_xor(q, 1);
            s += __shfl_xor(s, 2); q += __shfl_xor(q, 2);
            s += __shfl_xor(s, 4); q += __shfl_xor(q, 4);
            s += __shfl_xor(s, 8); q += __shfl_xor(q, 8);
            if (l15 == 0) {
                int r = fi * 16 + l4 * 4 + i;
                atomicAdd(&rsum[r], s);
                atomicAdd(&rsq[r], q);
            }
        }
    __syncthreads();
#pragma unroll
    for (int fi = 0; fi < 4; ++fi)
#pragma unroll
        for (int i = 0; i < 4; ++i) {
            int r = fi * 16 + l4 * 4 + i;
            float mu = rsum[r] * (1.f / 256.f);
            float var = rsq[r] * (1.f / 256.f) - mu * mu;
            float rstd = rsqrtf(var + 1e-5f);
#pragma unroll
            for (int fj = 0; fj < 2; ++fj) {
                int c = cbase + fj * 16 + l15;
                float v = (acc[fi][fj][i] - mu) * rstd * g2[c] + be2[c];
                hfc[(size_t)(lr0 + r) * 256 + c] = v;
                hfb[(size_t)(lr0 + r) * 256 + c] = (_Float16)v;
            }
        }
}

__global__ __launch_bounds__(512) void k_scores_final(
    const _Float16* __restrict__ hfb, const _Float16* __restrict__ wat,
    const float* __restrict__ va, const float* __restrict__ hfc,
    const int* __restrict__ food, const float* __restrict__ emb,
    float* __restrict__ out, int B, int g0) {
    __shared__ float part[8][64];
    __shared__ float at[64];
    __shared__ float pmax[2][256];
    int g = blockIdx.x;
    int b = g0 + g;
    int r0 = g * 64;
    int tid = threadIdx.x;
    int lane = tid & 63, wid = tid >> 6;
    int l15 = lane & 15, l4 = lane >> 4;
    int cbase = wid * 32;
    facc4 acc[4][2] = {};
#pragma unroll
    for (int kk = 0; kk < 8; ++kk) {
        half8 af[4], bf[2];
#pragma unroll
        for (int f = 0; f < 4; ++f)
            af[f] = *reinterpret_cast<const half8*>(
                hfb + (size_t)(r0 + f * 16 + l15) * 256 + kk * 32 + l4 * 8);
#pragma unroll
        for (int f = 0; f < 2; ++f)
            bf[f] = *reinterpret_cast<const half8*>(
                wat + (size_t)(cbase + f * 16 + l15) * 256 + kk * 32 + l4 * 8);
#pragma unroll
        for (int fi = 0; fi < 4; ++fi)
#pragma unroll
            for (int fj = 0; fj < 2; ++fj)
                acc[fi][fj] = __builtin_amdgcn_mfma_f32_16x16x32_f16(
                    af[fi], bf[fj], acc[fi][fj], 0, 0, 0);
    }
    float vac[2];
#pragma unroll
    for (int fj = 0; fj < 2; ++fj) vac[fj] = va[cbase + fj * 16 + l15];
#pragma unroll
    for (int fi = 0; fi < 4; ++fi)
#pragma unroll
        for (int i = 0; i < 4; ++i) {
            float v = tanhf(acc[fi][0][i]) * vac[0] + tanhf(acc[fi][1][i]) * vac[1];
            v += __shfl_xor(v, 1); v += __shfl_xor(v, 2);
            v += __shfl_xor(v, 4); v += __shfl_xor(v, 8);
            if (l15 == 0) part[wid][fi * 16 + l4 * 4 + i] = v;
        }
    __syncthreads();
    if (tid < 64) {
        float sc = part[0][tid] + part[1][tid] + part[2][tid] + part[3][tid] +
                   part[4][tid] + part[5][tid] + part[6][tid] + part[7][tid];
        float m = sc;
        for (int o = 32; o; o >>= 1) m = fmaxf(m, __shfl_xor(m, o));
        float ex = expf(sc - m);
        float s = ex;
        for (int o = 32; o; o >>= 1) s += __shfl_xor(s, o);
        float a = ex / (s + 1e-16f);
        at[tid] = a;
        out[(size_t)B * 512 + (size_t)b * 64 + tid] = a;
    }
    __syncthreads();
    {
        int c = tid & 255, half = tid >> 8;
        float m = -1e30f;
        for (int l = half * 32; l < half * 32 + 32; ++l)
            m = fmaxf(m, hfc[(size_t)(r0 + l) * 256 + c] * at[l]);
        pmax[half][c] = m;
    }
    __syncthreads();
    if (tid < 256) {
        out[(size_t)b * 256 + tid] = fmaxf(pmax[0][tid], pmax[1][tid]);
        out[(size_t)B * 256 + (size_t)b * 256 + tid] =
            emb[(size_t)food[b] * 256 + tid];
    }
}

// ---------------------------------------------------------------------------
extern "C" void kernel_launch(void* const* d_in, const int* in_sizes, int n_in,
                              void* d_out, int out_size, void* d_ws, size_t ws_size,
                              hipStream_t stream) {
    const float* x   = (const float*)d_in[0];
    const float* ea  = (const float*)d_in[1];
    const int*   ei  = (const int*)d_in[2];
    const int*   food= (const int*)d_in[4];
    const float* W1  = (const float*)d_in[5];
    const float* as1 = (const float*)d_in[6];
    const float* ad1 = (const float*)d_in[7];
    const float* We1 = (const float*)d_in[8];
    const float* ae1 = (const float*)d_in[9];
    const float* b1  = (const float*)d_in[10];
    const float* g1  = (const float*)d_in[11];
    const float* be1 = (const float*)d_in[12];
    const float* W2  = (const float*)d_in[13];
    const float* as2 = (const float*)d_in[14];
    const float* ad2 = (const float*)d_in[15];
    const float* We2 = (const float*)d_in[16];
    const float* ae2 = (const float*)d_in[17];
    const float* b2  = (const float*)d_in[18];
    const float* g2  = (const float*)d_in[19];
    const float* be2 = (const float*)d_in[20];
    const float* Wa  = (const float*)d_in[21];
    const float* va  = (const float*)d_in[22];
    const float* emb = (const float*)d_in[23];
    float* out = (float*)d_out;

    const int N  = in_sizes[0] / 55;
    const int E  = in_sizes[2] / 2;
    const int B  = in_sizes[4];
    const int Ef = E + N;
    const int LPG = N / B;

    char* w = (char*)d_ws;
    size_t off = 0;
    auto take = [&](size_t bytes) -> char* {
        char* p = w + off;
        off = (off + bytes + 255) & ~(size_t)255;
        return p;
    };
    int*      deg  = (int*)take((size_t)N * 4);
    float*    mea  = (float*)take((size_t)N * 6 * 4);
    int*      coff = (int*)take((size_t)(N + 1) * 4);
    int*      fill = (int*)take((size_t)N * 4);
    int*      eid  = (int*)take((size_t)Ef * 4);
    float*    ead1 = (float*)take((size_t)Ef * 4 * 4);
    float*    ead2 = (float*)take((size_t)Ef * 4);
    float*    fold = (float*)take(4096 * 4);
    float*    ss1  = (float*)take((size_t)N * 4 * 4);
    float*    sd1  = (float*)take((size_t)N * 4 * 4);
    float*    ss2  = (float*)take((size_t)N * 4);
    float*    sd2  = (float*)take((size_t)N * 4);
    _Float16* xbT  = (_Float16*)take((size_t)N * 64 * 2);
    _Float16* w1t  = (_Float16*)take((size_t)1024 * 64 * 2);
    _Float16* w2t  = (_Float16*)take((size_t)256 * 1024 * 2);
    _Float16* wat  = (_Float16*)take((size_t)256 * 256 * 2);
    size_t smallEnd = off;

    int G = B;
    while (G > 2 && smallEnd + (size_t)G * 32768 + 2ull * G * 131072 + 768 > ws_size) G >>= 1;
    _Float16* XA   = (_Float16*)take((size_t)G * 32768);
    _Float16* hpre = (_Float16*)take((size_t)G * 131072);
    _Float16* hln  = (_Float16*)take((size_t)G * 131072);
    _Float16* h2t = hpre;                                        // dead after ln1
    float*    hfc = (float*)((char*)hpre + (size_t)G * 32768);
    _Float16* hfb = (_Float16*)((char*)hpre + (size_t)G * 98304);

    hipMemsetAsync(deg, 0, (size_t)N * 4, stream);
    hipMemsetAsync(mea, 0, (size_t)N * 6 * 4, stream);
    hipMemsetAsync(fill, 0, (size_t)N * 4, stream);

    k_fold<<<12, 256, 0, stream>>>(We1, ae1, We2, ae2, W1, as1, ad1, W2, as2, ad2, fold);
    k_cast_w<<<(1024 * 64 + 256 * 1024 + 256 * 256 + 255) / 256, 256, 0, stream>>>(
        W1, W2, Wa, w1t, w2t, wat);
    k_cast_xt<<<(N * 64 + 255) / 256, 256, 0, stream>>>(x, xbT, N);
    k_ssd1<<<(N + 255) / 256, 256, 0, stream>>>(x, fold + 64, fold + 320, ss1, sd1, N);
    k_edge_accum<<<(E + 255) / 256, 256, 0, stream>>>(ei, ea, deg, mea, E);
    k_scan<<<1, 1024, 0, stream>>>(deg, coff, N);
    k_fill<<<(Ef + 255) / 256, 256, 0, stream>>>(ei, coff, fill, eid, E, Ef);
    k_eadot<<<(Ef + 255) / 256, 256, 0, stream>>>(ea, mea, deg, fold, fold + 32,
                                                  ead1, ead2, E, Ef);

    for (int g0 = 0; g0 < B; g0 += G) {
        int Gc = (g0 + G <= B) ? G : (B - g0);
        int n0 = g0 * LPG;
        int NC = Gc * LPG;
        k_pbuild1<<<Gc, 512, 0, stream>>>(xbT, N, coff, eid, ei, ead1, ss1, sd1,
                                          XA, NC, E, g0);
        k_gemm_heads<<<dim3(2, NC / 128, 4), 256, 0, stream>>>(XA, NC, w1t, hpre);
        k_ln1<<<NC / 4, 256, 0, stream>>>(hpre, b1, g1, be1, fold + 1024, fold + 2048,
                                          hln, ss2, sd2, n0);
        k_gemm2<<<dim3(NC / 128, 2), 256, 0, stream>>>(w2t, hln, h2t, NC);
        k_graph2<<<Gc, 512, 0, stream>>>(h2t, NC, coff, eid, ei, ead2, ss2, sd2,
                                         b2, g2, be2, hfc, hfb, E, g0);
        k_scores_final<<<Gc, 512, 0, stream>>>(hfb, wat, va, hfc, food, emb,
                                               out, B, g0);
    }
}

// Round 10
// 243.971 us; speedup vs baseline: 1.1030x; 1.0650x over previous
//
#include <hip/hip_runtime.h>
#include <cstdint>
#include <cstddef>

// ---------------------------------------------------------------------------
// GATExtractPart round 10: MFMA-fragment-order layouts for wat / hfb / x
// so direct-global fragment loads are contiguous 1KB per wave (were 64-line
// scattered). Same lane->element mapping; pure address permutation.
// fragment order for a [rows][K] f16 operand: ((tile16)*KG + kg)*512 + lane*8 + e
//   lane = (row&15) + 16*((k>>3)&3), e = k&7, kg = k>>5.
// ---------------------------------------------------------------------------

#define LEAKY_SLOPE 0.2f

typedef __attribute__((ext_vector_type(8))) _Float16 half8;
typedef __attribute__((ext_vector_type(4))) float facc4;

__global__ void k_fold(const float* __restrict__ We1, const float* __restrict__ ae1,
                       const float* __restrict__ We2, const float* __restrict__ ae2,
                       const float* __restrict__ W1, const float* __restrict__ as1,
                       const float* __restrict__ ad1,
                       const float* __restrict__ W2, const float* __restrict__ as2,
                       const float* __restrict__ ad2, float* __restrict__ fold) {
    int t = blockIdx.x * blockDim.x + threadIdx.x;
    if (t < 24) {
        int k = t >> 2, h = t & 3;
        float s = 0.f;
        for (int c = 0; c < 256; ++c) s += We1[k * 1024 + h * 256 + c] * ae1[h * 256 + c];
        fold[t] = s;
    } else if (t >= 24 && t < 30) {
        int k = t - 24;
        float s = 0.f;
        for (int c = 0; c < 256; ++c) s += We2[k * 256 + c] * ae2[c];
        fold[32 + k] = s;
    } else if (t >= 64 && t < 284) {
        int i = t - 64, k = i >> 2, h = i & 3;
        float s = 0.f;
        for (int c = 0; c < 256; ++c) s += W1[k * 1024 + h * 256 + c] * as1[h * 256 + c];
        fold[64 + i] = s;
    } else if (t >= 320 && t < 540) {
        int i = t - 320, k = i >> 2, h = i & 3;
        float s = 0.f;
        for (int c = 0; c < 256; ++c) s += W1[k * 1024 + h * 256 + c] * ad1[h * 256 + c];
        fold[320 + i] = s;
    } else if (t >= 1024 && t < 2048) {
        int k = t - 1024;
        float s = 0.f;
        for (int c = 0; c < 256; ++c) s += W2[k * 256 + c] * as2[c];
        fold[1024 + k] = s;
    } else if (t >= 2048 && t < 3072) {
        int k = t - 2048;
        float s = 0.f;
        for (int c = 0; c < 256; ++c) s += W2[k * 256 + c] * ad2[c];
        fold[2048 + k] = s;
    }
}

// w1t/w2t: row-major-transposed (LDS-staged consumers, coalesced already).
// wat: FRAGMENT ORDER: dst = (cg*8 + kg)*512 + ((c&15) + 16*((k>>3)&3))*8 + (k&7)
__global__ void k_cast_w(const float* __restrict__ W1, const float* __restrict__ W2,
                         const float* __restrict__ Wa, _Float16* __restrict__ w1t,
                         _Float16* __restrict__ w2t, _Float16* __restrict__ wat) {
    int idx = blockIdx.x * blockDim.x + threadIdx.x;
    if (idx < 1024 * 64) {
        int c = idx >> 6, k = idx & 63;
        w1t[idx] = (k < 55) ? (_Float16)W1[(size_t)k * 1024 + c] : (_Float16)0.f;
    } else if (idx < 1024 * 64 + 256 * 1024) {
        int i = idx - 1024 * 64;
        int c = i >> 10, k = i & 1023;
        w2t[i] = (_Float16)W2[(size_t)k * 256 + c];
    } else if (idx < 1024 * 64 + 256 * 1024 + 256 * 256) {
        int i = idx - 1024 * 64 - 256 * 1024;
        int c = i >> 8, k = i & 255;
        int dst = ((c >> 4) * 8 + (k >> 5)) * 512 + ((c & 15) + 16 * ((k >> 3) & 3)) * 8 + (k & 7);
        wat[dst] = (_Float16)Wa[(size_t)k * 256 + c];
    }
}

// x in per-graph fragment order: per graph 4096 elems.
// dst = g*4096 + ((k>>4)*2 + (nl>>5))*512 + ((k&15) + 16*((nl>>3)&3))*8 + (nl&7)
__global__ void k_cast_xf(const float* __restrict__ x, _Float16* __restrict__ xbf, int N) {
    int idx = blockIdx.x * blockDim.x + threadIdx.x;
    if (idx >= N * 64) return;
    int n = idx >> 6, k = idx & 63;
    _Float16 v = (k < 55) ? (_Float16)x[(size_t)n * 55 + k] : (_Float16)0.f;
    int g = n >> 6, nl = n & 63;
    size_t dst = (size_t)g * 4096 +
                 (((k >> 4) * 2 + (nl >> 5)) * 512 +
                  ((k & 15) + 16 * ((nl >> 3) & 3)) * 8 + (nl & 7));
    xbf[dst] = v;
}

__global__ void k_ssd1(const float* __restrict__ x, const float* __restrict__ wa1,
                       const float* __restrict__ wd1, float* __restrict__ ss1,
                       float* __restrict__ sd1, int N) {
    int n = blockIdx.x * blockDim.x + threadIdx.x;
    if (n >= N) return;
    float a0 = 0, a1 = 0, a2 = 0, a3 = 0, d0 = 0, d1 = 0, d2 = 0, d3 = 0;
    for (int k = 0; k < 55; ++k) {
        float xv = x[(size_t)n * 55 + k];
        float4 wa = *reinterpret_cast<const float4*>(&wa1[k * 4]);
        float4 wd = *reinterpret_cast<const float4*>(&wd1[k * 4]);
        a0 += xv * wa.x; a1 += xv * wa.y; a2 += xv * wa.z; a3 += xv * wa.w;
        d0 += xv * wd.x; d1 += xv * wd.y; d2 += xv * wd.z; d3 += xv * wd.w;
    }
    *reinterpret_cast<float4*>(&ss1[n * 4]) = make_float4(a0, a1, a2, a3);
    *reinterpret_cast<float4*>(&sd1[n * 4]) = make_float4(d0, d1, d2, d3);
}

__global__ void k_edge_accum(const int* __restrict__ ei, const float* __restrict__ ea,
                             int* __restrict__ deg, float* __restrict__ mea, int E) {
    int e = blockIdx.x * blockDim.x + threadIdx.x;
    if (e >= E) return;
    int d = ei[E + e];
    atomicAdd(&deg[d], 1);
#pragma unroll
    for (int k = 0; k < 6; ++k) atomicAdd(&mea[d * 6 + k], ea[e * 6 + k]);
}
__global__ void k_scan(const int* __restrict__ deg, int* __restrict__ off, int N) {
    __shared__ int part[1024];
    int t = threadIdx.x;
    int per = N / 1024;
    int base = t * per;
    int loc[32];
    int s = 0;
    for (int i = 0; i < per; ++i) { loc[i] = s; s += deg[base + i] + 1; }
    part[t] = s;
    __syncthreads();
    for (int o = 1; o < 1024; o <<= 1) {
        int v = (t >= o) ? part[t - o] : 0;
        __syncthreads();
        part[t] += v;
        __syncthreads();
    }
    int excl = (t == 0) ? 0 : part[t - 1];
    for (int i = 0; i < per; ++i) off[base + i] = excl + loc[i];
    if (t == 1023) off[N] = excl + s;
}
__global__ void k_fill(const int* __restrict__ ei, const int* __restrict__ coff,
                       int* __restrict__ fill, int* __restrict__ eid, int E, int Ef) {
    int e = blockIdx.x * blockDim.x + threadIdx.x;
    if (e >= Ef) return;
    int d = (e < E) ? ei[E + e] : (e - E);
    int pos = coff[d] + atomicAdd(&fill[d], 1);
    eid[pos] = e;
}
__global__ void k_eadot(const float* __restrict__ ea, const float* __restrict__ mea,
                        const int* __restrict__ deg,
                        const float* __restrict__ we1, const float* __restrict__ we2,
                        float* __restrict__ ead1, float* __restrict__ ead2, int E, int Ef) {
    int e = blockIdx.x * blockDim.x + threadIdx.x;
    if (e >= Ef) return;
    float buf[6];
    const float* eap;
    if (e < E) {
        eap = ea + (size_t)e * 6;
    } else {
        int n = e - E;
        float inv = 1.f / fmaxf((float)deg[n], 1.f);
#pragma unroll
        for (int k = 0; k < 6; ++k) buf[k] = mea[(size_t)n * 6 + k] * inv;
        eap = buf;
    }
    float v[4] = {};
    float v2 = 0.f;
#pragma unroll
    for (int k = 0; k < 6; ++k) {
        float a = eap[k];
#pragma unroll
        for (int h = 0; h < 4; ++h) v[h] += a * we1[k * 4 + h];
        v2 += a * we2[k];
    }
#pragma unroll
    for (int h = 0; h < 4; ++h) ead1[(size_t)e * 4 + h] = v[h];
    ead2[e] = v2;
}

__global__ __launch_bounds__(512) void k_pbuild1(
    const _Float16* __restrict__ xbf,
    const int* __restrict__ coff, const int* __restrict__ eid, const int* __restrict__ ei,
    const float* __restrict__ ead1, const float* __restrict__ ss1,
    const float* __restrict__ sd1,
    _Float16* __restrict__ XA, int ldxa, int E, int g0) {
    __shared__ _Float16 Pm[4][64 * 64];
    __shared__ float llds[384][4];
    __shared__ int slds[384];
    int g = blockIdx.x;
    int ng = (g0 + g) * 64;
    int lr0 = g * 64;
    int tid = threadIdx.x;
    int lane = tid & 63, wid = tid >> 6;
    int l15 = lane & 15, l4 = lane >> 4;
    for (int i = tid; i < 4 * 64 * 64 / 8; i += 512)
        *reinterpret_cast<int4*>(&Pm[0][0] + i * 8) = int4{0, 0, 0, 0};
    int pbase = coff[ng];
    int pcnt = coff[ng + 64] - pbase;
    if (pcnt > 384) pcnt = 384;
    for (int p = tid; p < pcnt; p += 512) {
        int e = eid[pbase + p];
        int s, d;
        if (e < E) { s = ei[e]; d = ei[E + e]; } else { s = e - E; d = s; }
        slds[p] = s - ng;
        float4 sv = *reinterpret_cast<const float4*>(&ss1[s * 4]);
        float4 dv = *reinterpret_cast<const float4*>(&sd1[d * 4]);
        float4 ev = *reinterpret_cast<const float4*>(&ead1[(size_t)e * 4]);
        float v0 = sv.x + dv.x + ev.x, v1 = sv.y + dv.y + ev.y;
        float v2 = sv.z + dv.z + ev.z, v3 = sv.w + dv.w + ev.w;
        llds[p][0] = (v0 > 0.f) ? v0 : LEAKY_SLOPE * v0;
        llds[p][1] = (v1 > 0.f) ? v1 : LEAKY_SLOPE * v1;
        llds[p][2] = (v2 > 0.f) ? v2 : LEAKY_SLOPE * v2;
        llds[p][3] = (v3 > 0.f) ? v3 : LEAKY_SLOPE * v3;
    }
    __syncthreads();
    if (tid < 256) {
        int dst = tid >> 2, h = tid & 3;
        int p0 = coff[ng + dst] - pbase, p1 = coff[ng + dst + 1] - pbase;
        float m = -1e30f;
        for (int p = p0; p < p1; ++p) m = fmaxf(m, llds[p][h]);
        float sm = 0.f;
        for (int p = p0; p < p1; ++p) sm += expf(llds[p][h] - m);
        float iv = 1.f / (sm + 1e-16f);
        for (int p = p0; p < p1; ++p) {
            int src = slds[p];
            int pos = dst * 64 + (((src >> 3) ^ (dst & 7)) << 3) + (src & 7);
            Pm[h][pos] = (_Float16)((float)Pm[h][pos] + expf(llds[p][h] - m) * iv);
        }
    }
    __syncthreads();
    int head = wid >> 1, fjh = wid & 1;
    const _Float16* xg = xbf + (size_t)(g0 + g) * 4096;
    facc4 acc[4][2] = {};
#pragma unroll
    for (int kk = 0; kk < 2; ++kk) {
        half8 af[4], bf[2];
#pragma unroll
        for (int f = 0; f < 4; ++f) {
            int arow = f * 16 + l15;
            af[f] = *reinterpret_cast<const half8*>(
                &Pm[head][arow * 64 + (((kk * 4 + l4) ^ (arow & 7)) << 3)]);
        }
#pragma unroll
        for (int f = 0; f < 2; ++f)
            bf[f] = *reinterpret_cast<const half8*>(
                xg + (((fjh * 2 + f) * 2 + kk) * 512 + lane * 8));
#pragma unroll
        for (int fi = 0; fi < 4; ++fi)
#pragma unroll
            for (int fj = 0; fj < 2; ++fj)
                acc[fi][fj] = __builtin_amdgcn_mfma_f32_16x16x32_f16(
                    af[fi], bf[fj], acc[fi][fj], 0, 0, 0);
    }
#pragma unroll
    for (int fi = 0; fi < 4; ++fi)
#pragma unroll
        for (int fj = 0; fj < 2; ++fj)
#pragma unroll
            for (int i = 0; i < 4; ++i) {
                int r = fi * 16 + l4 * 4 + i;
                int k2 = fjh * 32 + fj * 16 + l15;
                XA[((size_t)head * ldxa + lr0 + r) * 64 + k2] = (_Float16)acc[fi][fj][i];
            }
}

__global__ __launch_bounds__(256) void k_gemm_heads(
    const _Float16* __restrict__ XA, int ldxa, const _Float16* __restrict__ w1t,
    _Float16* __restrict__ hpre) {
    int h = blockIdx.z;
    const _Float16* A = XA + (size_t)h * ldxa * 64;
    const _Float16* BT = w1t + (size_t)h * 256 * 64;
    __shared__ _Float16 As[128 * 64];
    __shared__ _Float16 Bs[128 * 64];
    int tid = threadIdx.x;
    int lane = tid & 63, wid = tid >> 6;
    int wr = wid >> 1, wc = wid & 1;
    int l15 = lane & 15, l4 = lane >> 4;
    int r0 = blockIdx.y * 128, c0 = blockIdx.x * 128;
    facc4 acc[4][4] = {};
#pragma unroll
    for (int i = 0; i < 4; ++i) {
        int ch = tid + 256 * i;
        int row = ch >> 3, col16 = ch & 7;
        int sw = col16 ^ (row & 7);
        *reinterpret_cast<int4*>(&As[row * 64 + sw * 8]) =
            *reinterpret_cast<const int4*>(A + (size_t)(r0 + row) * 64 + col16 * 8);
        *reinterpret_cast<int4*>(&Bs[row * 64 + sw * 8]) =
            *reinterpret_cast<const int4*>(BT + (size_t)(c0 + row) * 64 + col16 * 8);
    }
    __syncthreads();
#pragma unroll
    for (int kk = 0; kk < 2; ++kk) {
        half8 af[4], bf[4];
#pragma unroll
        for (int f = 0; f < 4; ++f) {
            int arow = wr * 64 + f * 16 + l15;
            int ac = (kk * 4 + l4) ^ (arow & 7);
            af[f] = *reinterpret_cast<const half8*>(&As[arow * 64 + ac * 8]);
            int brow = wc * 64 + f * 16 + l15;
            int bc = (kk * 4 + l4) ^ (brow & 7);
            bf[f] = *reinterpret_cast<const half8*>(&Bs[brow * 64 + bc * 8]);
        }
#pragma unroll
        for (int fi = 0; fi < 4; ++fi)
#pragma unroll
            for (int fj = 0; fj < 4; ++fj)
                acc[fi][fj] = __builtin_amdgcn_mfma_f32_16x16x32_f16(
                    af[fi], bf[fj], acc[fi][fj], 0, 0, 0);
    }
#pragma unroll
    for (int fi = 0; fi < 4; ++fi)
#pragma unroll
        for (int fj = 0; fj < 4; ++fj)
#pragma unroll
            for (int i = 0; i < 4; ++i) {
                int r = r0 + wr * 64 + fi * 16 + l4 * 4 + i;
                int cc = h * 256 + c0 + wc * 64 + fj * 16 + l15;
                hpre[(size_t)r * 1024 + cc] = (_Float16)acc[fi][fj][i];
            }
}

__global__ __launch_bounds__(256) void k_ln1(
    const _Float16* __restrict__ hpre, const float* __restrict__ b1,
    const float* __restrict__ g1, const float* __restrict__ be1,
    const float* __restrict__ w2a, const float* __restrict__ w2d,
    _Float16* __restrict__ hln, float* __restrict__ ss2, float* __restrict__ sd2,
    int n0) {
    int row = blockIdx.x * 4 + (threadIdx.x >> 6);
    int lane = threadIdx.x & 63;
    const _Float16* src = hpre + (size_t)row * 1024;
    float v[16];
    half8 h0 = *reinterpret_cast<const half8*>(src + lane * 8);
    half8 h1 = *reinterpret_cast<const half8*>(src + 512 + lane * 8);
    float lsum = 0.f, lsq = 0.f;
#pragma unroll
    for (int j = 0; j < 8; ++j) {
        v[j] = (float)h0[j] + b1[lane * 8 + j];
        v[8 + j] = (float)h1[j] + b1[512 + lane * 8 + j];
    }
#pragma unroll
    for (int j = 0; j < 16; ++j) { lsum += v[j]; lsq += v[j] * v[j]; }
    for (int o = 32; o; o >>= 1) { lsum += __shfl_xor(lsum, o); lsq += __shfl_xor(lsq, o); }
    float mu = lsum * (1.f / 1024.f);
    float var = lsq * (1.f / 1024.f) - mu * mu;
    float rstd = rsqrtf(var + 1e-5f);
    float s2 = 0.f, d2 = 0.f;
    half8 o0, o1;
#pragma unroll
    for (int j = 0; j < 8; ++j) {
        int c = lane * 8 + j;
        float t = fmaxf((v[j] - mu) * rstd * g1[c] + be1[c], 0.f);
        o0[j] = (_Float16)t;
        s2 += t * w2a[c]; d2 += t * w2d[c];
    }
#pragma unroll
    for (int j = 0; j < 8; ++j) {
        int c = 512 + lane * 8 + j;
        float t = fmaxf((v[8 + j] - mu) * rstd * g1[c] + be1[c], 0.f);
        o1[j] = (_Float16)t;
        s2 += t * w2a[c]; d2 += t * w2d[c];
    }
    *reinterpret_cast<half8*>(hln + (size_t)row * 1024 + lane * 8) = o0;
    *reinterpret_cast<half8*>(hln + (size_t)row * 1024 + 512 + lane * 8) = o1;
    for (int o = 32; o; o >>= 1) { s2 += __shfl_xor(s2, o); d2 += __shfl_xor(d2, o); }
    if (lane == 0) { ss2[n0 + row] = s2; sd2[n0 + row] = d2; }
}

__global__ __launch_bounds__(256) void k_gemm2(
    const _Float16* __restrict__ A, const _Float16* __restrict__ BT,
    _Float16* __restrict__ C, int ldc) {
    __shared__ _Float16 As[128 * 64];
    __shared__ _Float16 Bs[128 * 64];
    int tid = threadIdx.x;
    int lane = tid & 63, wid = tid >> 6;
    int wr = wid >> 1, wc = wid & 1;
    int l15 = lane & 15, l4 = lane >> 4;
    int r0 = blockIdx.y * 128, c0 = blockIdx.x * 128;
    facc4 acc[4][4] = {};
    for (int kt = 0; kt < 1024; kt += 64) {
#pragma unroll
        for (int i = 0; i < 4; ++i) {
            int ch = tid + 256 * i;
            int row = ch >> 3, col16 = ch & 7;
            int sw = col16 ^ (row & 7);
            *reinterpret_cast<int4*>(&As[row * 64 + sw * 8]) =
                *reinterpret_cast<const int4*>(A + (size_t)(r0 + row) * 1024 + kt + col16 * 8);
            *reinterpret_cast<int4*>(&Bs[row * 64 + sw * 8]) =
                *reinterpret_cast<const int4*>(BT + (size_t)(c0 + row) * 1024 + kt + col16 * 8);
        }
        __syncthreads();
#pragma unroll
        for (int kk = 0; kk < 2; ++kk) {
            half8 af[4], bf[4];
#pragma unroll
            for (int f = 0; f < 4; ++f) {
                int arow = wr * 64 + f * 16 + l15;
                int ac = (kk * 4 + l4) ^ (arow & 7);
                af[f] = *reinterpret_cast<const half8*>(&As[arow * 64 + ac * 8]);
                int brow = wc * 64 + f * 16 + l15;
                int bc = (kk * 4 + l4) ^ (brow & 7);
                bf[f] = *reinterpret_cast<const half8*>(&Bs[brow * 64 + bc * 8]);
            }
#pragma unroll
            for (int fi = 0; fi < 4; ++fi)
#pragma unroll
                for (int fj = 0; fj < 4; ++fj)
                    acc[fi][fj] = __builtin_amdgcn_mfma_f32_16x16x32_f16(
                        af[fi], bf[fj], acc[fi][fj], 0, 0, 0);
        }
        __syncthreads();
    }
#pragma unroll
    for (int fi = 0; fi < 4; ++fi)
#pragma unroll
        for (int fj = 0; fj < 4; ++fj)
#pragma unroll
            for (int i = 0; i < 4; ++i) {
                int r = r0 + wr * 64 + fi * 16 + l4 * 4 + i;
                int cc = c0 + wc * 64 + fj * 16 + l15;
                C[(size_t)r * ldc + cc] = (_Float16)acc[fi][fj][i];
            }
}

__global__ __launch_bounds__(512) void k_graph2(
    const _Float16* __restrict__ h2t, int ldh,
    const int* __restrict__ coff, const int* __restrict__ eid, const int* __restrict__ ei,
    const float* __restrict__ ead2, const float* __restrict__ ss2,
    const float* __restrict__ sd2,
    const float* __restrict__ b2, const float* __restrict__ g2,
    const float* __restrict__ be2,
    float* __restrict__ hfc, _Float16* __restrict__ hfb, int E, int g0) {
    __shared__ _Float16 Pm[64 * 64];
    __shared__ float llds[384];
    __shared__ int slds[384];
    __shared__ float rsum[64], rsq[64];
    int g = blockIdx.x;
    int ng = (g0 + g) * 64;
    int lr0 = g * 64;
    int tid = threadIdx.x;
    int lane = tid & 63, wid = tid >> 6;
    int l15 = lane & 15, l4 = lane >> 4;
    if (tid < 64) { rsum[tid] = 0.f; rsq[tid] = 0.f; }
    for (int i = tid; i < 64 * 64 / 8; i += 512)
        *reinterpret_cast<int4*>(&Pm[0] + i * 8) = int4{0, 0, 0, 0};
    int pbase = coff[ng];
    int pcnt = coff[ng + 64] - pbase;
    if (pcnt > 384) pcnt = 384;
    for (int p = tid; p < pcnt; p += 512) {
        int e = eid[pbase + p];
        int s, d;
        if (e < E) { s = ei[e]; d = ei[E + e]; } else { s = e - E; d = s; }
        slds[p] = s - ng;
        float v = ss2[s] + sd2[d] + ead2[e];
        llds[p] = (v > 0.f) ? v : LEAKY_SLOPE * v;
    }
    __syncthreads();
    if (tid < 64) {
        int dst = tid;
        int p0 = coff[ng + dst] - pbase, p1 = coff[ng + dst + 1] - pbase;
        float m = -1e30f;
        for (int p = p0; p < p1; ++p) m = fmaxf(m, llds[p]);
        float sm = 0.f;
        for (int p = p0; p < p1; ++p) sm += expf(llds[p] - m);
        float iv = 1.f / (sm + 1e-16f);
        for (int p = p0; p < p1; ++p) {
            int src = slds[p];
            int pos = dst * 64 + (((src >> 3) ^ (dst & 7)) << 3) + (src & 7);
            Pm[pos] = (_Float16)((float)Pm[pos] + expf(llds[p] - m) * iv);
        }
    }
    __syncthreads();
    facc4 acc[4][2] = {};
    int cbase = wid * 32;
#pragma unroll
    for (int kk = 0; kk < 2; ++kk) {
        half8 af[4], bf[2];
#pragma unroll
        for (int f = 0; f < 4; ++f) {
            int arow = f * 16 + l15;
            af[f] = *reinterpret_cast<const half8*>(
                &Pm[arow * 64 + (((kk * 4 + l4) ^ (arow & 7)) << 3)]);
        }
#pragma unroll
        for (int f = 0; f < 2; ++f) {
            int c = cbase + f * 16 + l15;
            bf[f] = *reinterpret_cast<const half8*>(
                h2t + (size_t)c * ldh + lr0 + kk * 32 + l4 * 8);
        }
#pragma unroll
        for (int fi = 0; fi < 4; ++fi)
#pragma unroll
            for (int fj = 0; fj < 2; ++fj)
                acc[fi][fj] = __builtin_amdgcn_mfma_f32_16x16x32_f16(
                    af[fi], bf[fj], acc[fi][fj], 0, 0, 0);
    }
    float bb[2];
#pragma unroll
    for (int fj = 0; fj < 2; ++fj) bb[fj] = b2[cbase + fj * 16 + l15];
#pragma unroll
    for (int fi = 0; fi < 4; ++fi)
#pragma unroll
        for (int i = 0; i < 4; ++i) {
            float s = 0.f, q = 0.f;
#pragma unroll
            for (int fj = 0; fj < 2; ++fj) {
                float v = acc[fi][fj][i] + bb[fj];
                acc[fi][fj][i] = v;
                s += v; q += v * v;
            }
            s += __shfl_xor(s, 1); q += __shfl_xor(q, 1);
            s += __shfl_xor(s, 2); q += __shfl_xor(q, 2);
            s += __shfl_xor(s, 4); q += __shfl_xor(q, 4);
            s += __shfl_xor(s, 8); q += __shfl_xor(q, 8);
            if (l15 == 0) {
                int r = fi * 16 + l4 * 4 + i;
                atomicAdd(&rsum[r], s);
                atomicAdd(&rsq[r], q);
            }
        }
    __syncthreads();
    // epilogue: hfc row-major f32; hfb in FRAGMENT ORDER per graph:
    // dst = g*16384 + (fi*8 + (c>>5))*512 + ((r&15) + 16*((c>>3)&3))*8 + (c&7)
#pragma unroll
    for (int fi = 0; fi < 4; ++fi)
#pragma unroll
        for (int i = 0; i < 4; ++i) {
            int r = fi * 16 + l4 * 4 + i;
            float mu = rsum[r] * (1.f / 256.f);
            float var = rsq[r] * (1.f / 256.f) - mu * mu;
            float rstd = rsqrtf(var + 1e-5f);
#pragma unroll
            for (int fj = 0; fj < 2; ++fj) {
                int c = cbase + fj * 16 + l15;
                float v = (acc[fi][fj][i] - mu) * rstd * g2[c] + be2[c];
                hfc[(size_t)(lr0 + r) * 256 + c] = v;
                size_t dst = (size_t)g * 16384 +
                             ((fi * 8 + (c >> 5)) * 512 +
                              ((r & 15) + 16 * ((c >> 3) & 3)) * 8 + (c & 7));
                hfb[dst] = (_Float16)v;
            }
        }
}

// --- per-graph fused scores + softmax + pool + emb (fragment-order A,B) ------
__global__ __launch_bounds__(512) void k_scores_final(
    const _Float16* __restrict__ hfb, const _Float16* __restrict__ wat,
    const float* __restrict__ va, const float* __restrict__ hfc,
    const int* __restrict__ food, const float* __restrict__ emb,
    float* __restrict__ out, int B, int g0) {
    __shared__ float part[8][64];
    __shared__ float at[64];
    __shared__ float pmax[2][256];
    int g = blockIdx.x;
    int b = g0 + g;
    int r0 = g * 64;
    int tid = threadIdx.x;
    int lane = tid & 63, wid = tid >> 6;
    int l15 = lane & 15, l4 = lane >> 4;
    int cbase = wid * 32;
    const _Float16* hg = hfb + (size_t)g * 16384;
    facc4 acc[4][2] = {};
#pragma unroll
    for (int kk = 0; kk < 8; ++kk) {
        half8 af[4], bf[2];
#pragma unroll
        for (int f = 0; f < 4; ++f)
            af[f] = *reinterpret_cast<const half8*>(hg + ((f * 8 + kk) * 512 + lane * 8));
#pragma unroll
        for (int f = 0; f < 2; ++f)
            bf[f] = *reinterpret_cast<const half8*>(
                wat + (((wid * 2 + f) * 8 + kk) * 512 + lane * 8));
#pragma unroll
        for (int fi = 0; fi < 4; ++fi)
#pragma unroll
            for (int fj = 0; fj < 2; ++fj)
                acc[fi][fj] = __builtin_amdgcn_mfma_f32_16x16x32_f16(
                    af[fi], bf[fj], acc[fi][fj], 0, 0, 0);
    }
    float vac[2];
#pragma unroll
    for (int fj = 0; fj < 2; ++fj) vac[fj] = va[cbase + fj * 16 + l15];
#pragma unroll
    for (int fi = 0; fi < 4; ++fi)
#pragma unroll
        for (int i = 0; i < 4; ++i) {
            float v = tanhf(acc[fi][0][i]) * vac[0] + tanhf(acc[fi][1][i]) * vac[1];
            v += __shfl_xor(v, 1); v += __shfl_xor(v, 2);
            v += __shfl_xor(v, 4); v += __shfl_xor(v, 8);
            if (l15 == 0) part[wid][fi * 16 + l4 * 4 + i] = v;
        }
    __syncthreads();
    if (tid < 64) {
        float sc = part[0][tid] + part[1][tid] + part[2][tid] + part[3][tid] +
                   part[4][tid] + part[5][tid] + part[6][tid] + part[7][tid];
        float m = sc;
        for (int o = 32; o; o >>= 1) m = fmaxf(m, __shfl_xor(m, o));
        float ex = expf(sc - m);
        float s = ex;
        for (int o = 32; o; o >>= 1) s += __shfl_xor(s, o);
        float a = ex / (s + 1e-16f);
        at[tid] = a;
        out[(size_t)B * 512 + (size_t)b * 64 + tid] = a;
    }
    __syncthreads();
    {
        int c = tid & 255, half = tid >> 8;
        float m = -1e30f;
        for (int l = half * 32; l < half * 32 + 32; ++l)
            m = fmaxf(m, hfc[(size_t)(r0 + l) * 256 + c] * at[l]);
        pmax[half][c] = m;
    }
    __syncthreads();
    if (tid < 256) {
        out[(size_t)b * 256 + tid] = fmaxf(pmax[0][tid], pmax[1][tid]);
        out[(size_t)B * 256 + (size_t)b * 256 + tid] =
            emb[(size_t)food[b] * 256 + tid];
    }
}

// ---------------------------------------------------------------------------
extern "C" void kernel_launch(void* const* d_in, const int* in_sizes, int n_in,
                              void* d_out, int out_size, void* d_ws, size_t ws_size,
                              hipStream_t stream) {
    const float* x   = (const float*)d_in[0];
    const float* ea  = (const float*)d_in[1];
    const int*   ei  = (const int*)d_in[2];
    const int*   food= (const int*)d_in[4];
    const float* W1  = (const float*)d_in[5];
    const float* as1 = (const float*)d_in[6];
    const float* ad1 = (const float*)d_in[7];
    const float* We1 = (const float*)d_in[8];
    const float* ae1 = (const float*)d_in[9];
    const float* b1  = (const float*)d_in[10];
    const float* g1  = (const float*)d_in[11];
    const float* be1 = (const float*)d_in[12];
    const float* W2  = (const float*)d_in[13];
    const float* as2 = (const float*)d_in[14];
    const float* ad2 = (const float*)d_in[15];
    const float* We2 = (const float*)d_in[16];
    const float* ae2 = (const float*)d_in[17];
    const float* b2  = (const float*)d_in[18];
    const float* g2  = (const float*)d_in[19];
    const float* be2 = (const float*)d_in[20];
    const float* Wa  = (const float*)d_in[21];
    const float* va  = (const float*)d_in[22];
    const float* emb = (const float*)d_in[23];
    float* out = (float*)d_out;

    const int N  = in_sizes[0] / 55;
    const int E  = in_sizes[2] / 2;
    const int B  = in_sizes[4];
    const int Ef = E + N;
    const int LPG = N / B;

    char* w = (char*)d_ws;
    size_t off = 0;
    auto take = [&](size_t bytes) -> char* {
        char* p = w + off;
        off = (off + bytes + 255) & ~(size_t)255;
        return p;
    };
    int*      deg  = (int*)take((size_t)N * 4);
    float*    mea  = (float*)take((size_t)N * 6 * 4);
    int*      coff = (int*)take((size_t)(N + 1) * 4);
    int*      fill = (int*)take((size_t)N * 4);
    int*      eid  = (int*)take((size_t)Ef * 4);
    float*    ead1 = (float*)take((size_t)Ef * 4 * 4);
    float*    ead2 = (float*)take((size_t)Ef * 4);
    float*    fold = (float*)take(4096 * 4);
    float*    ss1  = (float*)take((size_t)N * 4 * 4);
    float*    sd1  = (float*)take((size_t)N * 4 * 4);
    float*    ss2  = (float*)take((size_t)N * 4);
    float*    sd2  = (float*)take((size_t)N * 4);
    _Float16* xbf  = (_Float16*)take((size_t)N * 64 * 2);
    _Float16* w1t  = (_Float16*)take((size_t)1024 * 64 * 2);
    _Float16* w2t  = (_Float16*)take((size_t)256 * 1024 * 2);
    _Float16* wat  = (_Float16*)take((size_t)256 * 256 * 2);
    size_t smallEnd = off;

    int G = B;
    while (G > 2 && smallEnd + (size_t)G * 32768 + 2ull * G * 131072 + 768 > ws_size) G >>= 1;
    _Float16* XA   = (_Float16*)take((size_t)G * 32768);
    _Float16* hpre = (_Float16*)take((size_t)G * 131072);
    _Float16* hln  = (_Float16*)take((size_t)G * 131072);
    _Float16* h2t = hpre;                                        // dead after ln1
    float*    hfc = (float*)((char*)hpre + (size_t)G * 32768);
    _Float16* hfb = (_Float16*)((char*)hpre + (size_t)G * 98304);

    hipMemsetAsync(deg, 0, (size_t)N * 4, stream);
    hipMemsetAsync(mea, 0, (size_t)N * 6 * 4, stream);
    hipMemsetAsync(fill, 0, (size_t)N * 4, stream);

    k_fold<<<12, 256, 0, stream>>>(We1, ae1, We2, ae2, W1, as1, ad1, W2, as2, ad2, fold);
    k_cast_w<<<(1024 * 64 + 256 * 1024 + 256 * 256 + 255) / 256, 256, 0, stream>>>(
        W1, W2, Wa, w1t, w2t, wat);
    k_cast_xf<<<(N * 64 + 255) / 256, 256, 0, stream>>>(x, xbf, N);
    k_ssd1<<<(N + 255) / 256, 256, 0, stream>>>(x, fold + 64, fold + 320, ss1, sd1, N);
    k_edge_accum<<<(E + 255) / 256, 256, 0, stream>>>(ei, ea, deg, mea, E);
    k_scan<<<1, 1024, 0, stream>>>(deg, coff, N);
    k_fill<<<(Ef + 255) / 256, 256, 0, stream>>>(ei, coff, fill, eid, E, Ef);
    k_eadot<<<(Ef + 255) / 256, 256, 0, stream>>>(ea, mea, deg, fold, fold + 32,
                                                  ead1, ead2, E, Ef);

    for (int g0 = 0; g0 < B; g0 += G) {
        int Gc = (g0 + G <= B) ? G : (B - g0);
        int n0 = g0 * LPG;
        int NC = Gc * LPG;
        k_pbuild1<<<Gc, 512, 0, stream>>>(xbf, coff, eid, ei, ead1, ss1, sd1,
                                          XA, NC, E, g0);
        k_gemm_heads<<<dim3(2, NC / 128, 4), 256, 0, stream>>>(XA, NC, w1t, hpre);
        k_ln1<<<NC / 4, 256, 0, stream>>>(hpre, b1, g1, be1, fold + 1024, fold + 2048,
                                          hln, ss2, sd2, n0);
        k_gemm2<<<dim3(NC / 128, 2), 256, 0, stream>>>(w2t, hln, h2t, NC);
        k_graph2<<<Gc, 512, 0, stream>>>(h2t, NC, coff, eid, ei, ead2, ss2, sd2,
                                         b2, g2, be2, hfc, hfb, E, g0);
        k_scores_final<<<Gc, 512, 0, stream>>>(hfb, wat, va, hfc, food, emb,
                                               out, B, g0);
    }
}